// Round 8
// baseline (180.274 us; speedup 1.0000x reference)
//
#include <hip/hip_runtime.h>
#include <hip/hip_bf16.h>

typedef __attribute__((ext_vector_type(8))) short bf16x8;
typedef __attribute__((ext_vector_type(4))) float f32x4;
typedef __attribute__((ext_vector_type(16))) float f32x16;
typedef __attribute__((ext_vector_type(4))) unsigned int u32x4;
typedef __attribute__((ext_vector_type(2))) unsigned int u32x2;

#define Bn 8
#define Tn 2048
#define Kn 64
#define Hn 8
#define KSn 5
#define CHn 512
#define TPADn 2052  /* 4 zero rows + 2048 */

__device__ __forceinline__ unsigned short f2bf(float f) {
    unsigned int x = __builtin_bit_cast(unsigned int, f);
    unsigned int r = (x + 0x7fffu + ((x >> 16) & 1u)) >> 16;
    return (unsigned short)r;
}

__device__ __forceinline__ unsigned int cvt_pk_bf16(float lo, float hi) {
    unsigned int r;
    asm("v_cvt_pk_bf16_f32 %0, %1, %2" : "=v"(r) : "v"(lo), "v"(hi));
    return r;
}

__device__ __forceinline__ float fast_exp2(float x) {
#if __has_builtin(__builtin_amdgcn_exp2f)
    return __builtin_amdgcn_exp2f(x);
#else
    return exp2f(x);
#endif
}

// cross-half (lane ^ 32) merges: validated shfl_xor path (rounds 1-4).
__device__ __forceinline__ float xhalf_max(float v) {
    return fmaxf(v, __shfl_xor(v, 32));
}
__device__ __forceinline__ float xhalf_add(float v) {
    return v + __shfl_xor(v, 32);
}

// distinct-operand two-register permute (validated in P-repack since round 1)
__device__ __forceinline__ u32x2 pl32swap(unsigned int x, unsigned int y) {
#if __has_builtin(__builtin_amdgcn_permlane32_swap)
    return __builtin_amdgcn_permlane32_swap(x, y, false, false);
#else
    unsigned int xs = (unsigned int)__shfl_xor((int)x, 32);
    unsigned int ys = (unsigned int)__shfl_xor((int)y, 32);
    int hi = (threadIdx.x & 63) >> 5;
    u32x2 r;
    r[0] = hi ? ys : x;   // {x.lo | y.lo}
    r[1] = hi ? y : xs;   // {x.hi | y.hi}
    return r;
#endif
}

__device__ __forceinline__ void gload_lds16(const void* g, void* l) {
    __builtin_amdgcn_global_load_lds(
        (const __attribute__((address_space(1))) void*)g,
        (__attribute__((address_space(3))) void*)l, 16, 0, 0);
}

// ---------------- prep: conversions + padded x + weight reformat + scale folding ----
__global__ void prep_kernel(const float* __restrict__ x,
                            const float* __restrict__ wq, const float* __restrict__ bq,
                            const float* __restrict__ wk, const float* __restrict__ bk,
                            const float* __restrict__ wv,
                            const float* __restrict__ wu,
                            unsigned short* __restrict__ x_pad,
                            unsigned short* __restrict__ w2q, unsigned short* __restrict__ w2k,
                            unsigned short* __restrict__ w2v,
                            unsigned short* __restrict__ wu_b,
                            float* __restrict__ bqs, float* __restrict__ bks)
{
    // 64^-0.25 * sqrt(log2(e)): scores come out pre-multiplied by log2(e)
    const float inv_scale = 0.424660900144f;
    const int N0 = Bn*TPADn*Kn;
    const int N1 = KSn*CHn*Kn;
    const int total = N0 + 3*N1 + CHn*Kn + 2*CHn;
    for (int i = blockIdx.x*blockDim.x + threadIdx.x; i < total; i += gridDim.x*blockDim.x) {
        if (i < N0) {
            int b = i / (TPADn*Kn);
            int rem = i - b*(TPADn*Kn);
            int p = rem >> 6, ic = rem & 63;
            x_pad[i] = (p < 4) ? (unsigned short)0
                               : f2bf(x[((size_t)b*Tn + (p - 4))*Kn + ic]);
            continue;
        }
        int r = i - N0;
        if (r < 3*N1) {
            int conv = r / N1; int rr = r - conv*N1;
            int j = rr / (CHn*Kn); int rc = rr - j*(CHn*Kn);
            int c = rc >> 6; int ic = rc & 63;
            const float* w = (conv==0) ? wq : ((conv==1) ? wk : wv);
            float s = (conv==2) ? 1.0f : inv_scale;
            unsigned short* dst = (conv==0) ? w2q : ((conv==1) ? w2k : w2v);
            dst[rr] = f2bf(w[(c*Kn + ic)*KSn + j] * s);
            continue;
        }
        r -= 3*N1;
        if (r < CHn*Kn) { wu_b[r] = f2bf(wu[r]); continue; }
        r -= CHn*Kn;
        if (r < CHn) { bqs[r] = bq[r]*inv_scale; continue; }
        r -= CHn;
        bks[r] = bk[r]*inv_scale;
    }
}

// ---------------- conv v4: register weights, LDS-staged x (dbuf), 8 t-tiles/block ---
__global__ __launch_bounds__(256) void conv_v4(
    const unsigned short* __restrict__ x_pad,
    const unsigned short* __restrict__ w2q, const unsigned short* __restrict__ w2k,
    const unsigned short* __restrict__ w2v,
    const float* __restrict__ bqs, const float* __restrict__ bks,
    unsigned short* __restrict__ q_s, unsigned short* __restrict__ k_s,
    unsigned short* __restrict__ v_t)
{
    __shared__ __align__(16) unsigned short xs[2][72*64];
    __shared__ __align__(16) unsigned short ts[64*64];
    const int tg = blockIdx.x;
    const int c0 = blockIdx.y * 64;
    const int zz = blockIdx.z;
    const int conv = zz >> 3, b = zz & 7;
    const unsigned short* w2 = (conv==0) ? w2q : ((conv==1) ? w2k : w2v);
    const float* bias = (conv==0) ? bqs : ((conv==1) ? bks : nullptr);
    unsigned short* outp = (conv==0) ? q_s : ((conv==1) ? k_s : v_t);
    const int tid = threadIdx.x;
    const int wid = tid >> 6, l = tid & 63;
    const int lr = l & 15, lh = l >> 4;
    const int wt = wid & 1, wc = wid >> 1;

    bf16x8 wf[5][2][2];
    #pragma unroll
    for (int j = 0; j < 5; ++j)
        #pragma unroll
        for (int kk = 0; kk < 2; ++kk)
            #pragma unroll
            for (int n2 = 0; n2 < 2; ++n2)
                wf[j][kk][n2] = *(const bf16x8*)
                    &w2[(j*CHn + c0 + wc*32 + n2*16 + lr)*Kn + kk*32 + lh*8];
    float bv0 = bias ? bias[c0 + wc*32 + lr]      : 0.0f;
    float bv1 = bias ? bias[c0 + wc*32 + 16 + lr] : 0.0f;

    const int swz_row = l >> 3;
    const int src_inrow = ((l & 7) << 4) ^ (swz_row << 4);

    int buf = 0;
    {
        const char* base = (const char*)(x_pad + (size_t)b*TPADn*Kn);
        int p0 = tg*512;
        for (int i = wid; i < 9; i += 4) {
            const char* src = base + (size_t)(p0 + i*8 + swz_row)*128 + src_inrow;
            gload_lds16(src, (char*)&xs[0][0] + i*1024);
        }
    }
    __syncthreads();

    for (int tt = 0; tt < 8; ++tt) {
        const int t0 = (tg*8 + tt)*64;
        if (tt < 7) {
            const char* base = (const char*)(x_pad + (size_t)b*TPADn*Kn);
            int p0 = t0 + 64;
            for (int i = wid; i < 9; i += 4) {
                const char* src = base + (size_t)(p0 + i*8 + swz_row)*128 + src_inrow;
                gload_lds16(src, (char*)&xs[buf^1][0] + i*1024);
            }
        }
        const char* xb = (const char*)&xs[buf][0];
        f32x4 acc[2][2] = {};
        #pragma unroll
        for (int j = 0; j < 5; ++j)
            #pragma unroll
            for (int kk = 0; kk < 2; ++kk) {
                #pragma unroll
                for (int m = 0; m < 2; ++m) {
                    int row = wt*32 + m*16 + lr + j;
                    bf16x8 a = *(const bf16x8*)
                        (xb + row*128 + ((kk*64 + lh*16) ^ ((row & 7) << 4)));
                    acc[m][0] = __builtin_amdgcn_mfma_f32_16x16x32_bf16(a, wf[j][kk][0], acc[m][0], 0, 0, 0);
                    acc[m][1] = __builtin_amdgcn_mfma_f32_16x16x32_bf16(a, wf[j][kk][1], acc[m][1], 0, 0, 0);
                }
            }
        __syncthreads();
        #pragma unroll
        for (int m = 0; m < 2; ++m)
            #pragma unroll
            for (int n2 = 0; n2 < 2; ++n2) {
                float bv = n2 ? bv1 : bv0;
                int cl = wc*32 + n2*16 + lr;
                #pragma unroll
                for (int reg = 0; reg < 4; ++reg) {
                    int tl = wt*32 + m*16 + lh*4 + reg;
                    ts[(tl*64 + cl) ^ ((tl & 7) << 3)] = f2bf(acc[m][n2][reg] + bv);
                }
            }
        __syncthreads();
        if (conv < 2) {
            #pragma unroll
            for (int it = 0; it < 2; ++it) {
                int idx = tid + it*256;
                int tl = idx >> 3, hl = idx & 7;
                unsigned short tmp[8];
                #pragma unroll
                for (int dl = 0; dl < 8; ++dl)
                    tmp[dl] = ts[(tl*64 + hl + 8*dl) ^ ((tl & 7) << 3)];
                size_t el = ((size_t)(b*Hn + hl)*Tn + t0 + tl)*Kn + (c0 >> 3);
                *(u32x4*)&outp[el] = *(u32x4*)tmp;
            }
        } else {
            #pragma unroll
            for (int it = 0; it < 2; ++it) {
                int idx = tid + it*256;
                int tc = idx >> 6, cl2 = idx & 63;
                int hl = cl2 & 7, dl = cl2 >> 3;
                unsigned short tmp[8];
                #pragma unroll
                for (int i2 = 0; i2 < 8; ++i2)
                    tmp[i2] = ts[((tc*8 + i2)*64 + cl2) ^ (((tc*8 + i2) & 7) << 3)];
                size_t el = ((size_t)(b*Hn + hl)*Kn + (c0 >> 3) + dl)*Tn + t0 + tc*8;
                *(u32x4*)&outp[el] = *(u32x4*)tmp;
            }
        }
        buf ^= 1;
    }
}

// -------- flash attention v6: asm-pinned K/V loads, counted vmcnt, dist-2 pipeline --
__global__ __launch_bounds__(256, 3) void attn_kernel(
    const unsigned short* __restrict__ q_s, const unsigned short* __restrict__ k_s,
    const unsigned short* __restrict__ v_t, unsigned short* __restrict__ attn2)
{
    __shared__ __align__(16) unsigned char lds_raw[4*4096];
    const int tid = threadIdx.x;
    const int wid = tid >> 6, l = tid & 63;
    const int lq = l & 31, hi = l >> 5;
    const int bx = blockIdx.x;                   // 1024 blocks
    const int bh = (bx & 7)*8 + ((bx >> 3) & 7); // 8 heads per XCD (K+V fits L2)
    // balanced chunk-group permutation: per-CU pg set {15-j0, j0, 8+j0, 7-j0} sums 30
    const int j = bx >> 6, gg = j >> 2, ii = j & 3;
    const int pg = (gg==0) ? 15-ii : (gg==1) ? ii : (gg==2) ? 8+ii : 7-ii;
    const int chunk = pg*4 + wid;
    const int qw = chunk * 32;
    const unsigned short* qp = q_s + (size_t)bh*Tn*Kn;
    const unsigned short* kp = k_s + (size_t)bh*Tn*Kn;
    const unsigned short* vp = v_t + (size_t)bh*Kn*Tn;
    unsigned short* op = attn2 + (size_t)bh*Tn*Kn;
    char* myLds = (char*)lds_raw + wid*4096;
    const int qg = qw + lq;

    // all Q/K/V loads are volatile asm: issue position & vmcnt counting are OURS.
    auto ldK = [&](bf16x8 (&kb)[4], int t) {
        const unsigned short* a = kp + (t*32 + lq)*Kn + hi*8;
        asm volatile("global_load_dwordx4 %0, %1, off"           : "=v"(kb[0]) : "v"(a));
        asm volatile("global_load_dwordx4 %0, %1, off offset:32" : "=v"(kb[1]) : "v"(a));
        asm volatile("global_load_dwordx4 %0, %1, off offset:64" : "=v"(kb[2]) : "v"(a));
        asm volatile("global_load_dwordx4 %0, %1, off offset:96" : "=v"(kb[3]) : "v"(a));
    };
    auto ldV = [&](bf16x8 (&vb)[4], int t) {
        const unsigned short* a0 = vp + lq*Tn + t*32 + hi*8;
        const unsigned short* a1 = a0 + 32*Tn;
        asm volatile("global_load_dwordx4 %0, %1, off"           : "=v"(vb[0]) : "v"(a0));
        asm volatile("global_load_dwordx4 %0, %1, off offset:32" : "=v"(vb[1]) : "v"(a0));
        asm volatile("global_load_dwordx4 %0, %1, off"           : "=v"(vb[2]) : "v"(a1));
        asm volatile("global_load_dwordx4 %0, %1, off offset:32" : "=v"(vb[3]) : "v"(a1));
    };

    bf16x8 qf[4];
    {
        const unsigned short* qa = qp + (qw + lq)*Kn + hi*8;
        asm volatile("global_load_dwordx4 %0, %1, off"           : "=v"(qf[0]) : "v"(qa));
        asm volatile("global_load_dwordx4 %0, %1, off offset:32" : "=v"(qf[1]) : "v"(qa));
        asm volatile("global_load_dwordx4 %0, %1, off offset:64" : "=v"(qf[2]) : "v"(qa));
        asm volatile("global_load_dwordx4 %0, %1, off offset:96" : "=v"(qf[3]) : "v"(qa));
    }
    bf16x8 kb0[4], kb1[4], vb0[4], vb1[4];
    ldK(kb0, 0); ldV(vb0, 0);
    if (chunk >= 1) { ldK(kb1, 1); ldV(vb1, 1); }
    // tile 0's waitcnt drains Q,K0,V0 (leaves at most K1,V1 = 8 in flight)

    f32x16 o0 = (f32x16)(0.0f), o1 = (f32x16)(0.0f);
    float m_run = -1e30f, l_run = 0.f;

    auto tile = [&](int t, bf16x8 (&kb)[4], bf16x8 (&vb)[4]) {
        // invariant at entry: outstanding = {K(t),V(t)} [+ {K(t+1),V(t+1)} if issued]
        if (t < chunk) asm volatile("s_waitcnt vmcnt(8)" ::: "memory");
        else           asm volatile("s_waitcnt vmcnt(0)" ::: "memory");
        __builtin_amdgcn_sched_barrier(0);   // rule #18: pin MFMA after waitcnt
        const int s0 = t*32;
        // QK^T (swapped): C[s][q], one q-column per lane
        f32x16 s = (f32x16)(0.0f);
        #pragma unroll
        for (int m = 0; m < 4; ++m)
            s = __builtin_amdgcn_mfma_f32_32x32x16_bf16(kb[m], qf[m], s, 0, 0, 0);
        // issue K(t+2) into the just-consumed buffer (distance-2 cover)
        if (t + 2 <= chunk) ldK(kb, t + 2);
        if (t == chunk) {
            #pragma unroll
            for (int r = 0; r < 16; ++r) {
                int sg = s0 + (r & 3) + 8*(r >> 2) + 4*hi;
                if (sg > qg) s[r] = -1e30f;
            }
        }
        // tree max + cross-half merge
        float a8[8];
        #pragma unroll
        for (int r = 0; r < 8; ++r) a8[r] = fmaxf(s[r], s[r + 8]);
        float a4_0 = fmaxf(a8[0], a8[4]), a4_1 = fmaxf(a8[1], a8[5]);
        float a4_2 = fmaxf(a8[2], a8[6]), a4_3 = fmaxf(a8[3], a8[7]);
        float mt = fmaxf(fmaxf(a4_0, a4_1), fmaxf(a4_2, a4_3));
        mt = xhalf_max(mt);
        // defer-max (log2 domain, THR=8)
        if (!__all(mt <= m_run + 8.0f)) {
            float mn = fmaxf(m_run, mt);
            float alpha = fast_exp2(m_run - mn);
            m_run = mn;
            l_run *= alpha;
            #pragma unroll
            for (int r = 0; r < 16; ++r) { o0[r] *= alpha; o1[r] *= alpha; }
        }
        float ps[4] = {0.f, 0.f, 0.f, 0.f};
        #pragma unroll
        for (int r = 0; r < 16; ++r) {
            float p = fast_exp2(s[r] - m_run);
            s[r] = p;
            ps[r & 3] += p;
        }
        float sum = (ps[0] + ps[1]) + (ps[2] + ps[3]);
        l_run += xhalf_add(sum);
        // repack P' -> B fragments (in-register; distinct-operand permlane swaps)
        unsigned int W[8];
        #pragma unroll
        for (int rp = 0; rp < 8; ++rp)
            W[rp] = cvt_pk_bf16(s[2*rp], s[2*rp + 1]);
        u32x4 bw[2];
        #pragma unroll
        for (int m = 0; m < 2; ++m)
            #pragma unroll
            for (int jp = 0; jp < 2; ++jp) {
                u32x2 sw = pl32swap(W[jp + 4*m], W[jp + 4*m + 2]);
                bw[m][jp]     = sw[0];
                bw[m][jp + 2] = sw[1];
            }
        // O^T += V^T * P'
        o0 = __builtin_amdgcn_mfma_f32_32x32x16_bf16(vb[0], __builtin_bit_cast(bf16x8, bw[0]), o0, 0, 0, 0);
        o0 = __builtin_amdgcn_mfma_f32_32x32x16_bf16(vb[1], __builtin_bit_cast(bf16x8, bw[1]), o0, 0, 0, 0);
        o1 = __builtin_amdgcn_mfma_f32_32x32x16_bf16(vb[2], __builtin_bit_cast(bf16x8, bw[0]), o1, 0, 0, 0);
        o1 = __builtin_amdgcn_mfma_f32_32x32x16_bf16(vb[3], __builtin_bit_cast(bf16x8, bw[1]), o1, 0, 0, 0);
        // issue V(t+2) into the just-consumed buffer
        if (t + 2 <= chunk) ldV(vb, t + 2);
    };

    int t = 0;
    while (true) {
        tile(t, kb0, vb0);
        if (t == chunk) break;
        tile(t + 1, kb1, vb1);
        if (t + 1 == chunk) break;
        t += 2;
    }

    // epilogue: normalize, per-wave LDS transpose, coalesced 16B stores
    float inv_l = 1.0f / l_run;
    #pragma unroll
    for (int e = 0; e < 16; e += 2) {
        int dd = (e & 3) + 8*(e >> 2) + 4*hi;
        unsigned int wv0 = cvt_pk_bf16(o0[e]*inv_l, o0[e+1]*inv_l);
        *(unsigned int*)(myLds + ((lq*128 + dd*2)      ^ ((lq & 7) << 4))) = wv0;
        unsigned int wv1 = cvt_pk_bf16(o1[e]*inv_l, o1[e+1]*inv_l);
        *(unsigned int*)(myLds + ((lq*128 + 64 + dd*2) ^ ((lq & 7) << 4))) = wv1;
    }
    int q2 = l >> 1, hf = l & 1;
    #pragma unroll
    for (int o4 = 0; o4 < 4; ++o4) {
        u32x4 vr = *(u32x4*)(myLds + ((q2*128 + hf*64 + o4*16) ^ ((q2 & 7) << 4)));
        *(u32x4*)&op[(qw + q2)*Kn + hf*32 + o4*8] = vr;
    }
}

// ---------------- output projection: 16 rows/block, 4-way K-split + LDS reduce ------
__global__ __launch_bounds__(256) void proj_kernel(
    const unsigned short* __restrict__ attn, const unsigned short* __restrict__ wu_b,
    const float* __restrict__ bu, float* __restrict__ outp)
{
    __shared__ float red[4*16*66];
    const int r0 = blockIdx.x * 16;
    const int tid = threadIdx.x;
    const int w = tid >> 6, l = tid & 63;
    const int lr = l & 15, lh = l >> 4;
    f32x4 acc[4] = {};
    const int r = r0 + lr;
    const int bb = r >> 11, tt = r & 2047;
    #pragma unroll
    for (int ki = 0; ki < 4; ++ki) {
        int kk = w*4 + ki;
        int ch = kk*32 + lh*8;
        int hh = ch >> 6, dd = ch & 63;
        bf16x8 a = *(const bf16x8*)&attn[(size_t)((bb*Hn + hh)*Tn + tt)*Kn + dd];
        #pragma unroll
        for (int n = 0; n < 4; ++n) {
            bf16x8 bf = *(const bf16x8*)&wu_b[(n*16 + lr)*CHn + ch];
            acc[n] = __builtin_amdgcn_mfma_f32_16x16x32_bf16(a, bf, acc[n], 0, 0, 0);
        }
    }
    #pragma unroll
    for (int n = 0; n < 4; ++n)
        #pragma unroll
        for (int reg = 0; reg < 4; ++reg)
            red[w*1056 + (lh*4 + reg)*66 + n*16 + lr] = acc[n][reg];
    __syncthreads();
    #pragma unroll
    for (int it = 0; it < 4; ++it) {
        int idx = tid + it*256;
        int rl = idx >> 6, ko = idx & 63;
        float s = red[rl*66 + ko] + red[1056 + rl*66 + ko]
                + red[2112 + rl*66 + ko] + red[3168 + rl*66 + ko] + bu[ko];
        outp[(size_t)(r0 + rl)*Kn + ko] = s;
    }
}

extern "C" void kernel_launch(void* const* d_in, const int* in_sizes, int n_in,
                              void* d_out, int out_size, void* d_ws, size_t ws_size,
                              hipStream_t stream)
{
    const float* x  = (const float*)d_in[0];
    const float* wq = (const float*)d_in[1];
    const float* bq = (const float*)d_in[2];
    const float* wk = (const float*)d_in[3];
    const float* bk = (const float*)d_in[4];
    const float* wv = (const float*)d_in[5];
    const float* wu = (const float*)d_in[6];
    const float* bu = (const float*)d_in[7];
    float* outp = (float*)d_out;

    char* ws = (char*)d_ws;
    size_t off = 0;
    auto alloc = [&](size_t bytes) {
        char* p = ws + off;
        off = (off + bytes + 255) & ~(size_t)255;
        return p;
    };
    unsigned short* x_pad = (unsigned short*)alloc((size_t)Bn*TPADn*Kn*2);
    unsigned short* w2q  = (unsigned short*)alloc((size_t)KSn*CHn*Kn*2);
    unsigned short* w2k  = (unsigned short*)alloc((size_t)KSn*CHn*Kn*2);
    unsigned short* w2v  = (unsigned short*)alloc((size_t)KSn*CHn*Kn*2);
    unsigned short* wu_b = (unsigned short*)alloc((size_t)CHn*Kn*2);
    float*  bqs = (float*)alloc(CHn*4);
    float*  bks = (float*)alloc(CHn*4);
    unsigned short* q_s  = (unsigned short*)alloc((size_t)Bn*Hn*Tn*Kn*2);
    unsigned short* k_s  = (unsigned short*)alloc((size_t)Bn*Hn*Tn*Kn*2);
    unsigned short* v_t  = (unsigned short*)alloc((size_t)Bn*Hn*Tn*Kn*2);
    unsigned short* attn = (unsigned short*)alloc((size_t)Bn*Tn*CHn*2);

    prep_kernel<<<2048, 256, 0, stream>>>(x, wq, bq, wk, bk, wv, wu,
                                          x_pad, w2q, w2k, w2v, wu_b, bqs, bks);
    conv_v4<<<dim3(4, 8, 24), 256, 0, stream>>>(
        x_pad, w2q, w2k, w2v, bqs, bks, q_s, k_s, v_t);
    attn_kernel<<<1024, 256, 0, stream>>>(q_s, k_s, v_t, attn);
    proj_kernel<<<(Bn*Tn)/16, 256, 0, stream>>>(attn, wu_b, bu, outp);
}

// Round 10
// 130.438 us; speedup vs baseline: 1.3821x; 1.3821x over previous
//
#include <hip/hip_runtime.h>
#include <hip/hip_bf16.h>

typedef __attribute__((ext_vector_type(8))) short bf16x8;
typedef __attribute__((ext_vector_type(4))) float f32x4;
typedef __attribute__((ext_vector_type(16))) float f32x16;
typedef __attribute__((ext_vector_type(4))) unsigned int u32x4;
typedef __attribute__((ext_vector_type(2))) unsigned int u32x2;

#define Bn 8
#define Tn 2048
#define Kn 64
#define Hn 8
#define KSn 5
#define CHn 512
#define TPADn 2052  /* 4 zero rows + 2048 */

__device__ __forceinline__ unsigned short f2bf(float f) {
    unsigned int x = __builtin_bit_cast(unsigned int, f);
    unsigned int r = (x + 0x7fffu + ((x >> 16) & 1u)) >> 16;
    return (unsigned short)r;
}

__device__ __forceinline__ unsigned int cvt_pk_bf16(float lo, float hi) {
    unsigned int r;
    asm("v_cvt_pk_bf16_f32 %0, %1, %2" : "=v"(r) : "v"(lo), "v"(hi));
    return r;
}

__device__ __forceinline__ float fast_exp2(float x) {
#if __has_builtin(__builtin_amdgcn_exp2f)
    return __builtin_amdgcn_exp2f(x);
#else
    float r;
    asm("v_exp_f32 %0, %1" : "=v"(r) : "v"(x));
    return r;
#endif
}

// cross-half (lane ^ 32) merges: validated shfl_xor path (rounds 1-4,7-8).
__device__ __forceinline__ float xhalf_max(float v) {
    return fmaxf(v, __shfl_xor(v, 32));
}
__device__ __forceinline__ float xhalf_add(float v) {
    return v + __shfl_xor(v, 32);
}

// distinct-operand two-register permute (validated in P-repack since round 1)
__device__ __forceinline__ u32x2 pl32swap(unsigned int x, unsigned int y) {
#if __has_builtin(__builtin_amdgcn_permlane32_swap)
    return __builtin_amdgcn_permlane32_swap(x, y, false, false);
#else
    unsigned int xs = (unsigned int)__shfl_xor((int)x, 32);
    unsigned int ys = (unsigned int)__shfl_xor((int)y, 32);
    int hi = (threadIdx.x & 63) >> 5;
    u32x2 r;
    r[0] = hi ? ys : x;   // {x.lo | y.lo}
    r[1] = hi ? y : xs;   // {x.hi | y.hi}
    return r;
#endif
}

__device__ __forceinline__ void gload_lds16(const void* g, void* l) {
    __builtin_amdgcn_global_load_lds(
        (const __attribute__((address_space(1))) void*)g,
        (__attribute__((address_space(3))) void*)l, 16, 0, 0);
}

// ---------------- prep: conversions + padded x + weight reformat + scale folding ----
__global__ void prep_kernel(const float* __restrict__ x,
                            const float* __restrict__ wq, const float* __restrict__ bq,
                            const float* __restrict__ wk, const float* __restrict__ bk,
                            const float* __restrict__ wv,
                            const float* __restrict__ wu,
                            unsigned short* __restrict__ x_pad,
                            unsigned short* __restrict__ w2q, unsigned short* __restrict__ w2k,
                            unsigned short* __restrict__ w2v,
                            unsigned short* __restrict__ wu_b,
                            float* __restrict__ bqs, float* __restrict__ bks)
{
    // 64^-0.25 * sqrt(log2(e)): scores come out pre-multiplied by log2(e)
    const float inv_scale = 0.424660900144f;
    const int N0 = Bn*TPADn*Kn;
    const int N1 = KSn*CHn*Kn;
    const int total = N0 + 3*N1 + CHn*Kn + 2*CHn;
    for (int i = blockIdx.x*blockDim.x + threadIdx.x; i < total; i += gridDim.x*blockDim.x) {
        if (i < N0) {
            int b = i / (TPADn*Kn);
            int rem = i - b*(TPADn*Kn);
            int p = rem >> 6, ic = rem & 63;
            x_pad[i] = (p < 4) ? (unsigned short)0
                               : f2bf(x[((size_t)b*Tn + (p - 4))*Kn + ic]);
            continue;
        }
        int r = i - N0;
        if (r < 3*N1) {
            int conv = r / N1; int rr = r - conv*N1;
            int j = rr / (CHn*Kn); int rc = rr - j*(CHn*Kn);
            int c = rc >> 6; int ic = rc & 63;
            const float* w = (conv==0) ? wq : ((conv==1) ? wk : wv);
            float s = (conv==2) ? 1.0f : inv_scale;
            unsigned short* dst = (conv==0) ? w2q : ((conv==1) ? w2k : w2v);
            dst[rr] = f2bf(w[(c*Kn + ic)*KSn + j] * s);
            continue;
        }
        r -= 3*N1;
        if (r < CHn*Kn) { wu_b[r] = f2bf(wu[r]); continue; }
        r -= CHn*Kn;
        if (r < CHn) { bqs[r] = bq[r]*inv_scale; continue; }
        r -= CHn;
        bks[r] = bk[r]*inv_scale;
    }
}

// ---------------- conv v4: register weights, LDS-staged x (dbuf), 8 t-tiles/block ---
__global__ __launch_bounds__(256) void conv_v4(
    const unsigned short* __restrict__ x_pad,
    const unsigned short* __restrict__ w2q, const unsigned short* __restrict__ w2k,
    const unsigned short* __restrict__ w2v,
    const float* __restrict__ bqs, const float* __restrict__ bks,
    unsigned short* __restrict__ q_s, unsigned short* __restrict__ k_s,
    unsigned short* __restrict__ v_t)
{
    __shared__ __align__(16) unsigned short xs[2][72*64];
    __shared__ __align__(16) unsigned short ts[64*64];
    const int tg = blockIdx.x;
    const int c0 = blockIdx.y * 64;
    const int zz = blockIdx.z;
    const int conv = zz >> 3, b = zz & 7;
    const unsigned short* w2 = (conv==0) ? w2q : ((conv==1) ? w2k : w2v);
    const float* bias = (conv==0) ? bqs : ((conv==1) ? bks : nullptr);
    unsigned short* outp = (conv==0) ? q_s : ((conv==1) ? k_s : v_t);
    const int tid = threadIdx.x;
    const int wid = tid >> 6, l = tid & 63;
    const int lr = l & 15, lh = l >> 4;
    const int wt = wid & 1, wc = wid >> 1;

    bf16x8 wf[5][2][2];
    #pragma unroll
    for (int j = 0; j < 5; ++j)
        #pragma unroll
        for (int kk = 0; kk < 2; ++kk)
            #pragma unroll
            for (int n2 = 0; n2 < 2; ++n2)
                wf[j][kk][n2] = *(const bf16x8*)
                    &w2[(j*CHn + c0 + wc*32 + n2*16 + lr)*Kn + kk*32 + lh*8];
    float bv0 = bias ? bias[c0 + wc*32 + lr]      : 0.0f;
    float bv1 = bias ? bias[c0 + wc*32 + 16 + lr] : 0.0f;

    const int swz_row = l >> 3;
    const int src_inrow = ((l & 7) << 4) ^ (swz_row << 4);

    int buf = 0;
    {
        const char* base = (const char*)(x_pad + (size_t)b*TPADn*Kn);
        int p0 = tg*512;
        for (int i = wid; i < 9; i += 4) {
            const char* src = base + (size_t)(p0 + i*8 + swz_row)*128 + src_inrow;
            gload_lds16(src, (char*)&xs[0][0] + i*1024);
        }
    }
    __syncthreads();

    for (int tt = 0; tt < 8; ++tt) {
        const int t0 = (tg*8 + tt)*64;
        if (tt < 7) {
            const char* base = (const char*)(x_pad + (size_t)b*TPADn*Kn);
            int p0 = t0 + 64;
            for (int i = wid; i < 9; i += 4) {
                const char* src = base + (size_t)(p0 + i*8 + swz_row)*128 + src_inrow;
                gload_lds16(src, (char*)&xs[buf^1][0] + i*1024);
            }
        }
        const char* xb = (const char*)&xs[buf][0];
        f32x4 acc[2][2] = {};
        #pragma unroll
        for (int j = 0; j < 5; ++j)
            #pragma unroll
            for (int kk = 0; kk < 2; ++kk) {
                #pragma unroll
                for (int m = 0; m < 2; ++m) {
                    int row = wt*32 + m*16 + lr + j;
                    bf16x8 a = *(const bf16x8*)
                        (xb + row*128 + ((kk*64 + lh*16) ^ ((row & 7) << 4)));
                    acc[m][0] = __builtin_amdgcn_mfma_f32_16x16x32_bf16(a, wf[j][kk][0], acc[m][0], 0, 0, 0);
                    acc[m][1] = __builtin_amdgcn_mfma_f32_16x16x32_bf16(a, wf[j][kk][1], acc[m][1], 0, 0, 0);
                }
            }
        __syncthreads();
        #pragma unroll
        for (int m = 0; m < 2; ++m)
            #pragma unroll
            for (int n2 = 0; n2 < 2; ++n2) {
                float bv = n2 ? bv1 : bv0;
                int cl = wc*32 + n2*16 + lr;
                #pragma unroll
                for (int reg = 0; reg < 4; ++reg) {
                    int tl = wt*32 + m*16 + lh*4 + reg;
                    ts[(tl*64 + cl) ^ ((tl & 7) << 3)] = f2bf(acc[m][n2][reg] + bv);
                }
            }
        __syncthreads();
        if (conv < 2) {
            #pragma unroll
            for (int it = 0; it < 2; ++it) {
                int idx = tid + it*256;
                int tl = idx >> 3, hl = idx & 7;
                unsigned short tmp[8];
                #pragma unroll
                for (int dl = 0; dl < 8; ++dl)
                    tmp[dl] = ts[(tl*64 + hl + 8*dl) ^ ((tl & 7) << 3)];
                size_t el = ((size_t)(b*Hn + hl)*Tn + t0 + tl)*Kn + (c0 >> 3);
                *(u32x4*)&outp[el] = *(u32x4*)tmp;
            }
        } else {
            #pragma unroll
            for (int it = 0; it < 2; ++it) {
                int idx = tid + it*256;
                int tc = idx >> 6, cl2 = idx & 63;
                int hl = cl2 & 7, dl = cl2 >> 3;
                unsigned short tmp[8];
                #pragma unroll
                for (int i2 = 0; i2 < 8; ++i2)
                    tmp[i2] = ts[((tc*8 + i2)*64 + cl2) ^ (((tc*8 + i2) & 7) << 3)];
                size_t el = ((size_t)(b*Hn + hl)*Kn + (c0 >> 3) + dl)*Tn + t0 + tc*8;
                *(u32x4*)&outp[el] = *(u32x4*)tmp;
            }
        }
        buf ^= 1;
    }
}

// ---- flash attention v8: per-wave LDS staging (global_load_lds), half-split merge --
// Each wave owns an 8KB LDS slot; K/V tiles staged via global_load_lds (no VGPR
// lifetime for in-flight data => nothing to spill). Chunks>=32 split across 2 waves
// (max serial chain 32 tiles), merged via one barrier; chunks<32 solo, balanced.
__global__ __launch_bounds__(256, 3) void attn_kernel(
    const unsigned short* __restrict__ q_s, const unsigned short* __restrict__ k_s,
    const unsigned short* __restrict__ v_t, unsigned short* __restrict__ attn2)
{
    __shared__ __align__(16) unsigned char lds_raw[34816];  // 4x8KB stage + 2KB (m,l)
    const int tid = threadIdx.x;
    const int wid = tid >> 6, l = tid & 63;
    const int lq = l & 31, hi = l >> 5;
    const int bx = blockIdx.x;                   // 1536 blocks, heavy (split) first
    const int bh = (bx & 7)*8 + ((bx >> 3) & 7); // 8 heads per XCD (K+V fits L2)
    const int kb = bx >> 6;                      // 0..23
    int c, t0, t1, role;                         // role: 0 solo, 1 merger, 2 writer
    if (kb < 16) {   // split block: chunks {32+kb, 63-kb}; per pair: halves
        c = (wid < 2) ? (32 + kb) : (63 - kb);
        int L = c + 1, mid = L >> 1, h = wid & 1;
        t0 = h ? mid : 0; t1 = h ? L : mid;
        role = h ? 2 : 1;
    } else {         // solo block: chunks {i, 15-i, 16+i, 31-i}, constant total
        int i = kb - 16;
        c = (wid == 0) ? i : (wid == 1) ? 15 - i : (wid == 2) ? 16 + i : 31 - i;
        t0 = 0; t1 = c + 1; role = 0;
    }
    const int qw = c * 32;
    const unsigned short* qp = q_s + (size_t)bh*Tn*Kn;
    const char* kpc = (const char*)(k_s + (size_t)bh*Tn*Kn);
    const char* vpc = (const char*)(v_t + (size_t)bh*Kn*Tn);
    unsigned short* op = attn2 + (size_t)bh*Tn*Kn;
    const int qg = qw + lq;

    char* stK = (char*)lds_raw + wid*8192;   // [32 keys][64 d], 128B rows, slot^row&7
    char* stV = stK + 4096;                  // [64 d][32 s],   64B rows, slot^d&3

    const int kr = l >> 3, ks7 = l & 7;      // K stage lane decomposition
    const int vr = l >> 2, vs3 = l & 3;      // V stage lane decomposition
    auto stage = [&](int t) {
        const char* kt = kpc + (size_t)t*4096;
        #pragma unroll
        for (int i = 0; i < 4; ++i) {
            int row = i*8 + kr;
            gload_lds16(kt + row*128 + ((ks7 ^ (row & 7)) << 4), stK + i*1024);
        }
        const char* vt = vpc + (size_t)t*64;
        #pragma unroll
        for (int i = 0; i < 4; ++i) {
            int d = i*16 + vr;
            gload_lds16(vt + (size_t)d*4096 + ((vs3 ^ (d & 3)) << 4), stV + i*1024);
        }
    };

    bf16x8 qf[4];
    #pragma unroll
    for (int m = 0; m < 4; ++m)
        qf[m] = *(const bf16x8*)&qp[(qw + lq)*Kn + m*16 + hi*8];

    f32x16 o0 = (f32x16)(0.0f), o1 = (f32x16)(0.0f);
    float m_run = -1e30f, l_run = 0.f;

    stage(t0);
    for (int t = t0; t < t1; ++t) {
        asm volatile("s_waitcnt vmcnt(0)" ::: "memory");  // stage(t) landed
        __builtin_amdgcn_sched_barrier(0);
        // fragment reads from own LDS slot (swizzle-matched, conflict-light)
        bf16x8 kbf[4], vbf[2][2];
        #pragma unroll
        for (int m = 0; m < 4; ++m)
            kbf[m] = *(const bf16x8*)(stK + lq*128 + ((m*32 + hi*16) ^ ((lq & 7) << 4)));
        #pragma unroll
        for (int dn = 0; dn < 2; ++dn)
            #pragma unroll
            for (int ks = 0; ks < 2; ++ks)
                vbf[dn][ks] = *(const bf16x8*)
                    (stV + (dn*32 + lq)*64 + (((ks*2 + hi) << 4) ^ ((lq & 3) << 4)));
        asm volatile("s_waitcnt lgkmcnt(0)" ::: "memory"); // reads done before overwrite
        __builtin_amdgcn_sched_barrier(0);
        if (t + 1 < t1) stage(t + 1);                      // async fill under compute
        __builtin_amdgcn_sched_barrier(0);
        // QK^T (swapped): C[s][q], one q-column per lane
        const int s0 = t*32;
        f32x16 s = (f32x16)(0.0f);
        #pragma unroll
        for (int m = 0; m < 4; ++m)
            s = __builtin_amdgcn_mfma_f32_32x32x16_bf16(kbf[m], qf[m], s, 0, 0, 0);
        if (t == c) {
            #pragma unroll
            for (int r = 0; r < 16; ++r) {
                int sg = s0 + (r & 3) + 8*(r >> 2) + 4*hi;
                if (sg > qg) s[r] = -1e30f;
            }
        }
        float a8[8];
        #pragma unroll
        for (int r = 0; r < 8; ++r) a8[r] = fmaxf(s[r], s[r + 8]);
        float a4_0 = fmaxf(a8[0], a8[4]), a4_1 = fmaxf(a8[1], a8[5]);
        float a4_2 = fmaxf(a8[2], a8[6]), a4_3 = fmaxf(a8[3], a8[7]);
        float mt = fmaxf(fmaxf(a4_0, a4_1), fmaxf(a4_2, a4_3));
        mt = xhalf_max(mt);
        if (!__all(mt <= m_run + 8.0f)) {   // defer-max (log2 domain, THR=8)
            float mn = fmaxf(m_run, mt);
            float alpha = fast_exp2(m_run - mn);
            m_run = mn;
            l_run *= alpha;
            #pragma unroll
            for (int r = 0; r < 16; ++r) { o0[r] *= alpha; o1[r] *= alpha; }
        }
        float ps[4] = {0.f, 0.f, 0.f, 0.f};
        #pragma unroll
        for (int r = 0; r < 16; ++r) {
            float p = fast_exp2(s[r] - m_run);
            s[r] = p;
            ps[r & 3] += p;
        }
        float sum = (ps[0] + ps[1]) + (ps[2] + ps[3]);
        l_run += xhalf_add(sum);
        unsigned int W[8];
        #pragma unroll
        for (int rp = 0; rp < 8; ++rp)
            W[rp] = cvt_pk_bf16(s[2*rp], s[2*rp + 1]);
        u32x4 bw[2];
        #pragma unroll
        for (int m = 0; m < 2; ++m)
            #pragma unroll
            for (int jp = 0; jp < 2; ++jp) {
                u32x2 sw = pl32swap(W[jp + 4*m], W[jp + 4*m + 2]);
                bw[m][jp]     = sw[0];
                bw[m][jp + 2] = sw[1];
            }
        o0 = __builtin_amdgcn_mfma_f32_32x32x16_bf16(vbf[0][0], __builtin_bit_cast(bf16x8, bw[0]), o0, 0, 0, 0);
        o0 = __builtin_amdgcn_mfma_f32_32x32x16_bf16(vbf[0][1], __builtin_bit_cast(bf16x8, bw[1]), o0, 0, 0, 0);
        o1 = __builtin_amdgcn_mfma_f32_32x32x16_bf16(vbf[1][0], __builtin_bit_cast(bf16x8, bw[0]), o1, 0, 0, 0);
        o1 = __builtin_amdgcn_mfma_f32_32x32x16_bf16(vbf[1][1], __builtin_bit_cast(bf16x8, bw[1]), o1, 0, 0, 0);
    }

    // ---- half-split merge: writer drops (o,m,l) in its own (dead) stage slot ------
    if (role == 2) {
        float* po = (float*)stK;                       // own 8KB, stage is dead
        #pragma unroll
        for (int r = 0; r < 16; ++r) { po[l*32 + r] = o0[r]; po[l*32 + 16 + r] = o1[r]; }
        float* pml = (float*)(lds_raw + 32768) + wid*128 + l*2;
        pml[0] = m_run; pml[1] = l_run;
    }
    if (role) __syncthreads();
    if (role == 2) return;
    if (role == 1) {
        const float* po = (const float*)(lds_raw + (wid + 1)*8192);
        const float* pml = (const float*)(lds_raw + 32768) + (wid + 1)*128 + l*2;
        float m2 = pml[0], l2 = pml[1];
        float mf = fmaxf(m_run, m2);
        float a1 = fast_exp2(m_run - mf), a2 = fast_exp2(m2 - mf);
        l_run = l_run*a1 + l2*a2;
        #pragma unroll
        for (int r = 0; r < 16; ++r) {
            o0[r] = o0[r]*a1 + po[l*32 + r]*a2;
            o1[r] = o1[r]*a1 + po[l*32 + 16 + r]*a2;
        }
    }

    // epilogue: normalize, per-wave LDS transpose (own slot), coalesced 16B stores
    char* myLds = stK;
    float inv_l = 1.0f / l_run;
    #pragma unroll
    for (int e = 0; e < 16; e += 2) {
        int dd = (e & 3) + 8*(e >> 2) + 4*hi;
        unsigned int wv0 = cvt_pk_bf16(o0[e]*inv_l, o0[e+1]*inv_l);
        *(unsigned int*)(myLds + ((lq*128 + dd*2)      ^ ((lq & 7) << 4))) = wv0;
        unsigned int wv1 = cvt_pk_bf16(o1[e]*inv_l, o1[e+1]*inv_l);
        *(unsigned int*)(myLds + ((lq*128 + 64 + dd*2) ^ ((lq & 7) << 4))) = wv1;
    }
    int q2 = l >> 1, hf = l & 1;
    #pragma unroll
    for (int o4 = 0; o4 < 4; ++o4) {
        u32x4 vr2 = *(u32x4*)(myLds + ((q2*128 + hf*64 + o4*16) ^ ((q2 & 7) << 4)));
        *(u32x4*)&op[(qw + q2)*Kn + hf*32 + o4*8] = vr2;
    }
}

// ---------------- output projection: 16 rows/block, 4-way K-split + LDS reduce ------
__global__ __launch_bounds__(256) void proj_kernel(
    const unsigned short* __restrict__ attn, const unsigned short* __restrict__ wu_b,
    const float* __restrict__ bu, float* __restrict__ outp)
{
    __shared__ float red[4*16*66];
    const int r0 = blockIdx.x * 16;
    const int tid = threadIdx.x;
    const int w = tid >> 6, l = tid & 63;
    const int lr = l & 15, lh = l >> 4;
    f32x4 acc[4] = {};
    const int r = r0 + lr;
    const int bb = r >> 11, tt = r & 2047;
    #pragma unroll
    for (int ki = 0; ki < 4; ++ki) {
        int kk = w*4 + ki;
        int ch = kk*32 + lh*8;
        int hh = ch >> 6, dd = ch & 63;
        bf16x8 a = *(const bf16x8*)&attn[(size_t)((bb*Hn + hh)*Tn + tt)*Kn + dd];
        #pragma unroll
        for (int n = 0; n < 4; ++n) {
            bf16x8 bf = *(const bf16x8*)&wu_b[(n*16 + lr)*CHn + ch];
            acc[n] = __builtin_amdgcn_mfma_f32_16x16x32_bf16(a, bf, acc[n], 0, 0, 0);
        }
    }
    #pragma unroll
    for (int n = 0; n < 4; ++n)
        #pragma unroll
        for (int reg = 0; reg < 4; ++reg)
            red[w*1056 + (lh*4 + reg)*66 + n*16 + lr] = acc[n][reg];
    __syncthreads();
    #pragma unroll
    for (int it = 0; it < 4; ++it) {
        int idx = tid + it*256;
        int rl = idx >> 6, ko = idx & 63;
        float s = red[rl*66 + ko] + red[1056 + rl*66 + ko]
                + red[2112 + rl*66 + ko] + red[3168 + rl*66 + ko] + bu[ko];
        outp[(size_t)(r0 + rl)*Kn + ko] = s;
    }
}

extern "C" void kernel_launch(void* const* d_in, const int* in_sizes, int n_in,
                              void* d_out, int out_size, void* d_ws, size_t ws_size,
                              hipStream_t stream)
{
    const float* x  = (const float*)d_in[0];
    const float* wq = (const float*)d_in[1];
    const float* bq = (const float*)d_in[2];
    const float* wk = (const float*)d_in[3];
    const float* bk = (const float*)d_in[4];
    const float* wv = (const float*)d_in[5];
    const float* wu = (const float*)d_in[6];
    const float* bu = (const float*)d_in[7];
    float* outp = (float*)d_out;

    char* ws = (char*)d_ws;
    size_t off = 0;
    auto alloc = [&](size_t bytes) {
        char* p = ws + off;
        off = (off + bytes + 255) & ~(size_t)255;
        return p;
    };
    unsigned short* x_pad = (unsigned short*)alloc((size_t)Bn*TPADn*Kn*2);
    unsigned short* w2q  = (unsigned short*)alloc((size_t)KSn*CHn*Kn*2);
    unsigned short* w2k  = (unsigned short*)alloc((size_t)KSn*CHn*Kn*2);
    unsigned short* w2v  = (unsigned short*)alloc((size_t)KSn*CHn*Kn*2);
    unsigned short* wu_b = (unsigned short*)alloc((size_t)CHn*Kn*2);
    float*  bqs = (float*)alloc(CHn*4);
    float*  bks = (float*)alloc(CHn*4);
    unsigned short* q_s  = (unsigned short*)alloc((size_t)Bn*Hn*Tn*Kn*2);
    unsigned short* k_s  = (unsigned short*)alloc((size_t)Bn*Hn*Tn*Kn*2);
    unsigned short* v_t  = (unsigned short*)alloc((size_t)Bn*Hn*Tn*Kn*2);
    unsigned short* attn = (unsigned short*)alloc((size_t)Bn*Tn*CHn*2);

    prep_kernel<<<2048, 256, 0, stream>>>(x, wq, bq, wk, bk, wv, wu,
                                          x_pad, w2q, w2k, w2v, wu_b, bqs, bks);
    conv_v4<<<dim3(4, 8, 24), 256, 0, stream>>>(
        x_pad, w2q, w2k, w2v, bqs, bks, q_s, k_s, v_t);
    attn_kernel<<<1536, 256, 0, stream>>>(q_s, k_s, v_t, attn);
    proj_kernel<<<(Bn*Tn)/16, 256, 0, stream>>>(attn, wu_b, bu, outp);
}

// Round 11
// 129.191 us; speedup vs baseline: 1.3954x; 1.0096x over previous
//
#include <hip/hip_runtime.h>
#include <hip/hip_bf16.h>

typedef __attribute__((ext_vector_type(8))) short bf16x8;
typedef __attribute__((ext_vector_type(4))) float f32x4;
typedef __attribute__((ext_vector_type(16))) float f32x16;
typedef __attribute__((ext_vector_type(4))) unsigned int u32x4;
typedef __attribute__((ext_vector_type(2))) unsigned int u32x2;

#define Bn 8
#define Tn 2048
#define Kn 64
#define Hn 8
#define KSn 5
#define CHn 512
#define TPADn 2052  /* 4 zero rows + 2048 */

__device__ __forceinline__ unsigned short f2bf(float f) {
    unsigned int x = __builtin_bit_cast(unsigned int, f);
    unsigned int r = (x + 0x7fffu + ((x >> 16) & 1u)) >> 16;
    return (unsigned short)r;
}

__device__ __forceinline__ unsigned int cvt_pk_bf16(float lo, float hi) {
    unsigned int r;
    asm("v_cvt_pk_bf16_f32 %0, %1, %2" : "=v"(r) : "v"(lo), "v"(hi));
    return r;
}

__device__ __forceinline__ float fast_exp2(float x) {
#if __has_builtin(__builtin_amdgcn_exp2f)
    return __builtin_amdgcn_exp2f(x);
#else
    float r;
    asm("v_exp_f32 %0, %1" : "=v"(r) : "v"(x));
    return r;
#endif
}

// cross-half (lane ^ 32) merges: validated shfl_xor path (rounds 1-4,7-10).
__device__ __forceinline__ float xhalf_max(float v) {
    return fmaxf(v, __shfl_xor(v, 32));
}
__device__ __forceinline__ float xhalf_add(float v) {
    return v + __shfl_xor(v, 32);
}

// distinct-operand two-register permute (validated in P-repack since round 1)
__device__ __forceinline__ u32x2 pl32swap(unsigned int x, unsigned int y) {
#if __has_builtin(__builtin_amdgcn_permlane32_swap)
    return __builtin_amdgcn_permlane32_swap(x, y, false, false);
#else
    unsigned int xs = (unsigned int)__shfl_xor((int)x, 32);
    unsigned int ys = (unsigned int)__shfl_xor((int)y, 32);
    int hi = (threadIdx.x & 63) >> 5;
    u32x2 r;
    r[0] = hi ? ys : x;   // {x.lo | y.lo}
    r[1] = hi ? y : xs;   // {x.hi | y.hi}
    return r;
#endif
}

__device__ __forceinline__ void gload_lds16(const void* g, void* l) {
    __builtin_amdgcn_global_load_lds(
        (const __attribute__((address_space(1))) void*)g,
        (__attribute__((address_space(3))) void*)l, 16, 0, 0);
}

// ---------------- prep: conversions + padded x + weight reformat + scale folding ----
__global__ void prep_kernel(const float* __restrict__ x,
                            const float* __restrict__ wq, const float* __restrict__ bq,
                            const float* __restrict__ wk, const float* __restrict__ bk,
                            const float* __restrict__ wv,
                            const float* __restrict__ wu,
                            unsigned short* __restrict__ x_pad,
                            unsigned short* __restrict__ w2q, unsigned short* __restrict__ w2k,
                            unsigned short* __restrict__ w2v,
                            unsigned short* __restrict__ wu_b,
                            float* __restrict__ bqs, float* __restrict__ bks)
{
    // 64^-0.25 * sqrt(log2(e)): scores come out pre-multiplied by log2(e)
    const float inv_scale = 0.424660900144f;
    const int N0 = Bn*TPADn*Kn;
    const int N1 = KSn*CHn*Kn;
    const int total = N0 + 3*N1 + CHn*Kn + 2*CHn;
    for (int i = blockIdx.x*blockDim.x + threadIdx.x; i < total; i += gridDim.x*blockDim.x) {
        if (i < N0) {
            int b = i / (TPADn*Kn);
            int rem = i - b*(TPADn*Kn);
            int p = rem >> 6, ic = rem & 63;
            x_pad[i] = (p < 4) ? (unsigned short)0
                               : f2bf(x[((size_t)b*Tn + (p - 4))*Kn + ic]);
            continue;
        }
        int r = i - N0;
        if (r < 3*N1) {
            int conv = r / N1; int rr = r - conv*N1;
            int j = rr / (CHn*Kn); int rc = rr - j*(CHn*Kn);
            int c = rc >> 6; int ic = rc & 63;
            const float* w = (conv==0) ? wq : ((conv==1) ? wk : wv);
            float s = (conv==2) ? 1.0f : inv_scale;
            unsigned short* dst = (conv==0) ? w2q : ((conv==1) ? w2k : w2v);
            dst[rr] = f2bf(w[(c*Kn + ic)*KSn + j] * s);
            continue;
        }
        r -= 3*N1;
        if (r < CHn*Kn) { wu_b[r] = f2bf(wu[r]); continue; }
        r -= CHn*Kn;
        if (r < CHn) { bqs[r] = bq[r]*inv_scale; continue; }
        r -= CHn;
        bks[r] = bk[r]*inv_scale;
    }
}

// ---------------- conv v4: register weights, LDS-staged x (dbuf), 8 t-tiles/block ---
__global__ __launch_bounds__(256) void conv_v4(
    const unsigned short* __restrict__ x_pad,
    const unsigned short* __restrict__ w2q, const unsigned short* __restrict__ w2k,
    const unsigned short* __restrict__ w2v,
    const float* __restrict__ bqs, const float* __restrict__ bks,
    unsigned short* __restrict__ q_s, unsigned short* __restrict__ k_s,
    unsigned short* __restrict__ v_t)
{
    __shared__ __align__(16) unsigned short xs[2][72*64];
    __shared__ __align__(16) unsigned short ts[64*64];
    const int tg = blockIdx.x;
    const int c0 = blockIdx.y * 64;
    const int zz = blockIdx.z;
    const int conv = zz >> 3, b = zz & 7;
    const unsigned short* w2 = (conv==0) ? w2q : ((conv==1) ? w2k : w2v);
    const float* bias = (conv==0) ? bqs : ((conv==1) ? bks : nullptr);
    unsigned short* outp = (conv==0) ? q_s : ((conv==1) ? k_s : v_t);
    const int tid = threadIdx.x;
    const int wid = tid >> 6, l = tid & 63;
    const int lr = l & 15, lh = l >> 4;
    const int wt = wid & 1, wc = wid >> 1;

    bf16x8 wf[5][2][2];
    #pragma unroll
    for (int j = 0; j < 5; ++j)
        #pragma unroll
        for (int kk = 0; kk < 2; ++kk)
            #pragma unroll
            for (int n2 = 0; n2 < 2; ++n2)
                wf[j][kk][n2] = *(const bf16x8*)
                    &w2[(j*CHn + c0 + wc*32 + n2*16 + lr)*Kn + kk*32 + lh*8];
    float bv0 = bias ? bias[c0 + wc*32 + lr]      : 0.0f;
    float bv1 = bias ? bias[c0 + wc*32 + 16 + lr] : 0.0f;

    const int swz_row = l >> 3;
    const int src_inrow = ((l & 7) << 4) ^ (swz_row << 4);

    int buf = 0;
    {
        const char* base = (const char*)(x_pad + (size_t)b*TPADn*Kn);
        int p0 = tg*512;
        for (int i = wid; i < 9; i += 4) {
            const char* src = base + (size_t)(p0 + i*8 + swz_row)*128 + src_inrow;
            gload_lds16(src, (char*)&xs[0][0] + i*1024);
        }
    }
    __syncthreads();

    for (int tt = 0; tt < 8; ++tt) {
        const int t0 = (tg*8 + tt)*64;
        if (tt < 7) {
            const char* base = (const char*)(x_pad + (size_t)b*TPADn*Kn);
            int p0 = t0 + 64;
            for (int i = wid; i < 9; i += 4) {
                const char* src = base + (size_t)(p0 + i*8 + swz_row)*128 + src_inrow;
                gload_lds16(src, (char*)&xs[buf^1][0] + i*1024);
            }
        }
        const char* xb = (const char*)&xs[buf][0];
        f32x4 acc[2][2] = {};
        #pragma unroll
        for (int j = 0; j < 5; ++j)
            #pragma unroll
            for (int kk = 0; kk < 2; ++kk) {
                #pragma unroll
                for (int m = 0; m < 2; ++m) {
                    int row = wt*32 + m*16 + lr + j;
                    bf16x8 a = *(const bf16x8*)
                        (xb + row*128 + ((kk*64 + lh*16) ^ ((row & 7) << 4)));
                    acc[m][0] = __builtin_amdgcn_mfma_f32_16x16x32_bf16(a, wf[j][kk][0], acc[m][0], 0, 0, 0);
                    acc[m][1] = __builtin_amdgcn_mfma_f32_16x16x32_bf16(a, wf[j][kk][1], acc[m][1], 0, 0, 0);
                }
            }
        __syncthreads();
        #pragma unroll
        for (int m = 0; m < 2; ++m)
            #pragma unroll
            for (int n2 = 0; n2 < 2; ++n2) {
                float bv = n2 ? bv1 : bv0;
                int cl = wc*32 + n2*16 + lr;
                #pragma unroll
                for (int reg = 0; reg < 4; ++reg) {
                    int tl = wt*32 + m*16 + lh*4 + reg;
                    ts[(tl*64 + cl) ^ ((tl & 7) << 3)] = f2bf(acc[m][n2][reg] + bv);
                }
            }
        __syncthreads();
        if (conv < 2) {
            #pragma unroll
            for (int it = 0; it < 2; ++it) {
                int idx = tid + it*256;
                int tl = idx >> 3, hl = idx & 7;
                unsigned short tmp[8];
                #pragma unroll
                for (int dl = 0; dl < 8; ++dl)
                    tmp[dl] = ts[(tl*64 + hl + 8*dl) ^ ((tl & 7) << 3)];
                size_t el = ((size_t)(b*Hn + hl)*Tn + t0 + tl)*Kn + (c0 >> 3);
                *(u32x4*)&outp[el] = *(u32x4*)tmp;
            }
        } else {
            #pragma unroll
            for (int it = 0; it < 2; ++it) {
                int idx = tid + it*256;
                int tc = idx >> 6, cl2 = idx & 63;
                int hl = cl2 & 7, dl = cl2 >> 3;
                unsigned short tmp[8];
                #pragma unroll
                for (int i2 = 0; i2 < 8; ++i2)
                    tmp[i2] = ts[((tc*8 + i2)*64 + cl2) ^ (((tc*8 + i2) & 7) << 3)];
                size_t el = ((size_t)(b*Hn + hl)*Kn + (c0 >> 3) + dl)*Tn + t0 + tc*8;
                *(u32x4*)&outp[el] = *(u32x4*)tmp;
            }
        }
        buf ^= 1;
    }
}

// ---- flash attention v9: LDS staging + conflict-free merge + hoisted stage addrs ---
__global__ __launch_bounds__(256, 3) void attn_kernel(
    const unsigned short* __restrict__ q_s, const unsigned short* __restrict__ k_s,
    const unsigned short* __restrict__ v_t, unsigned short* __restrict__ attn2)
{
    __shared__ __align__(16) unsigned char lds_raw[34816];  // 4x8KB stage + 2KB (m,l)
    const int tid = threadIdx.x;
    const int wid = tid >> 6, l = tid & 63;
    const int lq = l & 31, hi = l >> 5;
    const int bx = blockIdx.x;                   // 1536 blocks, heavy (split) first
    const int bh = (bx & 7)*8 + ((bx >> 3) & 7); // 8 heads per XCD (K+V fits L2)
    const int kb = bx >> 6;                      // 0..23
    int c, t0, t1, role;                         // role: 0 solo, 1 merger, 2 writer
    if (kb < 16) {   // split block: chunks {32+kb, 63-kb}; per pair: halves
        c = (wid < 2) ? (32 + kb) : (63 - kb);
        int L = c + 1, mid = L >> 1, h = wid & 1;
        t0 = h ? mid : 0; t1 = h ? L : mid;
        role = h ? 2 : 1;
    } else {         // solo block: chunks {i, 15-i, 16+i, 31-i}, constant total
        int i = kb - 16;
        c = (wid == 0) ? i : (wid == 1) ? 15 - i : (wid == 2) ? 16 + i : 31 - i;
        t0 = 0; t1 = c + 1; role = 0;
    }
    const int qw = c * 32;
    const unsigned short* qp = q_s + (size_t)bh*Tn*Kn;
    const char* kpc = (const char*)(k_s + (size_t)bh*Tn*Kn);
    const char* vpc = (const char*)(v_t + (size_t)bh*Kn*Tn);
    unsigned short* op = attn2 + (size_t)bh*Tn*Kn;
    const int qg = qw + lq;

    char* stK = (char*)lds_raw + wid*8192;   // [32 keys][64 d], 128B rows, slot^row&7
    char* stV = stK + 4096;                  // [64 d][32 s],   64B rows, slot^d&3

    // loop-invariant per-lane source swizzle offsets ((i*8+kr)&7 == kr, (i*16+vr)&3 == vr&3)
    const int kr = l >> 3, ks7 = l & 7;
    const int vr = l >> 2, vs3 = l & 3;
    const int kSrcOff = kr*128 + ((ks7 ^ kr) << 4);
    const int vSrcOff = vr*4096 + ((vs3 ^ (vr & 3)) << 4);
    const char* ktp = kpc + (size_t)t0*4096 + kSrcOff;  // next K tile to stage
    const char* vtp = vpc + (size_t)t0*64   + vSrcOff;  // next V tile to stage
    auto stage = [&]() {
        gload_lds16(ktp,           stK);
        gload_lds16(ktp + 1024,    stK + 1024);
        gload_lds16(ktp + 2048,    stK + 2048);
        gload_lds16(ktp + 3072,    stK + 3072);
        gload_lds16(vtp,           stV);
        gload_lds16(vtp + 65536,   stV + 1024);
        gload_lds16(vtp + 131072,  stV + 2048);
        gload_lds16(vtp + 196608,  stV + 3072);
        ktp += 4096; vtp += 64;
    };

    bf16x8 qf[4];
    #pragma unroll
    for (int m = 0; m < 4; ++m)
        qf[m] = *(const bf16x8*)&qp[(qw + lq)*Kn + m*16 + hi*8];

    f32x16 o0 = (f32x16)(0.0f), o1 = (f32x16)(0.0f);
    float m_run = -1e30f, l_run = 0.f;

    stage();
    for (int t = t0; t < t1; ++t) {
        asm volatile("s_waitcnt vmcnt(0)" ::: "memory");  // stage(t) landed
        __builtin_amdgcn_sched_barrier(0);
        // fragment reads from own LDS slot (swizzle-matched)
        bf16x8 kbf[4], vbf[2][2];
        #pragma unroll
        for (int m = 0; m < 4; ++m)
            kbf[m] = *(const bf16x8*)(stK + lq*128 + ((m*32 + hi*16) ^ ((lq & 7) << 4)));
        #pragma unroll
        for (int dn = 0; dn < 2; ++dn)
            #pragma unroll
            for (int ks = 0; ks < 2; ++ks)
                vbf[dn][ks] = *(const bf16x8*)
                    (stV + (dn*32 + lq)*64 + (((ks*2 + hi) << 4) ^ ((lq & 3) << 4)));
        asm volatile("s_waitcnt lgkmcnt(0)" ::: "memory"); // reads done before overwrite
        __builtin_amdgcn_sched_barrier(0);
        if (t + 1 < t1) stage();                           // async fill under compute
        __builtin_amdgcn_sched_barrier(0);
        // QK^T (swapped): C[s][q], one q-column per lane
        const int s0 = t*32;
        f32x16 s = (f32x16)(0.0f);
        #pragma unroll
        for (int m = 0; m < 4; ++m)
            s = __builtin_amdgcn_mfma_f32_32x32x16_bf16(kbf[m], qf[m], s, 0, 0, 0);
        if (t == c) {
            #pragma unroll
            for (int r = 0; r < 16; ++r) {
                int sg = s0 + (r & 3) + 8*(r >> 2) + 4*hi;
                if (sg > qg) s[r] = -1e30f;
            }
        }
        float a8[8];
        #pragma unroll
        for (int r = 0; r < 8; ++r) a8[r] = fmaxf(s[r], s[r + 8]);
        float a4_0 = fmaxf(a8[0], a8[4]), a4_1 = fmaxf(a8[1], a8[5]);
        float a4_2 = fmaxf(a8[2], a8[6]), a4_3 = fmaxf(a8[3], a8[7]);
        float mt = fmaxf(fmaxf(a4_0, a4_1), fmaxf(a4_2, a4_3));
        mt = xhalf_max(mt);
        if (!__all(mt <= m_run + 8.0f)) {   // defer-max (log2 domain, THR=8)
            float mn = fmaxf(m_run, mt);
            float alpha = fast_exp2(m_run - mn);
            m_run = mn;
            l_run *= alpha;
            #pragma unroll
            for (int r = 0; r < 16; ++r) { o0[r] *= alpha; o1[r] *= alpha; }
        }
        float ps[4] = {0.f, 0.f, 0.f, 0.f};
        #pragma unroll
        for (int r = 0; r < 16; ++r) {
            float p = fast_exp2(s[r] - m_run);
            s[r] = p;
            ps[r & 3] += p;
        }
        float sum = (ps[0] + ps[1]) + (ps[2] + ps[3]);
        l_run += xhalf_add(sum);
        unsigned int W[8];
        #pragma unroll
        for (int rp = 0; rp < 8; ++rp)
            W[rp] = cvt_pk_bf16(s[2*rp], s[2*rp + 1]);
        u32x4 bw[2];
        #pragma unroll
        for (int m = 0; m < 2; ++m)
            #pragma unroll
            for (int jp = 0; jp < 2; ++jp) {
                u32x2 sw = pl32swap(W[jp + 4*m], W[jp + 4*m + 2]);
                bw[m][jp]     = sw[0];
                bw[m][jp + 2] = sw[1];
            }
        o0 = __builtin_amdgcn_mfma_f32_32x32x16_bf16(vbf[0][0], __builtin_bit_cast(bf16x8, bw[0]), o0, 0, 0, 0);
        o0 = __builtin_amdgcn_mfma_f32_32x32x16_bf16(vbf[0][1], __builtin_bit_cast(bf16x8, bw[1]), o0, 0, 0, 0);
        o1 = __builtin_amdgcn_mfma_f32_32x32x16_bf16(vbf[1][0], __builtin_bit_cast(bf16x8, bw[0]), o1, 0, 0, 0);
        o1 = __builtin_amdgcn_mfma_f32_32x32x16_bf16(vbf[1][1], __builtin_bit_cast(bf16x8, bw[1]), o1, 0, 0, 0);
    }

    // ---- half-split merge: COLUMN-MAJOR [r][lane] layout => conflict-free ---------
    if (role == 2) {
        float* po = (float*)stK;                       // own 8KB slot, stage is dead
        #pragma unroll
        for (int r = 0; r < 16; ++r) {
            po[r*64 + l]        = o0[r];
            po[(16 + r)*64 + l] = o1[r];
        }
        float* pml = (float*)(lds_raw + 32768 + wid*512);
        pml[l] = m_run; pml[64 + l] = l_run;
    }
    if (role) __syncthreads();
    if (role == 2) return;
    if (role == 1) {
        const float* po = (const float*)(lds_raw + (wid + 1)*8192);
        const float* pml = (const float*)(lds_raw + 32768 + (wid + 1)*512);
        float m2 = pml[l], l2 = pml[64 + l];
        float mf = fmaxf(m_run, m2);
        float a1 = fast_exp2(m_run - mf), a2 = fast_exp2(m2 - mf);
        l_run = l_run*a1 + l2*a2;
        #pragma unroll
        for (int r = 0; r < 16; ++r) {
            o0[r] = o0[r]*a1 + po[r*64 + l]*a2;
            o1[r] = o1[r]*a1 + po[(16 + r)*64 + l]*a2;
        }
        m_run = mf;
    }

    // epilogue: normalize, per-wave LDS transpose (own slot), coalesced 16B stores
    char* myLds = stK;
    float inv_l = 1.0f / l_run;
    #pragma unroll
    for (int e = 0; e < 16; e += 2) {
        int dd = (e & 3) + 8*(e >> 2) + 4*hi;
        unsigned int wv0 = cvt_pk_bf16(o0[e]*inv_l, o0[e+1]*inv_l);
        *(unsigned int*)(myLds + ((lq*128 + dd*2)      ^ ((lq & 7) << 4))) = wv0;
        unsigned int wv1 = cvt_pk_bf16(o1[e]*inv_l, o1[e+1]*inv_l);
        *(unsigned int*)(myLds + ((lq*128 + 64 + dd*2) ^ ((lq & 7) << 4))) = wv1;
    }
    int q2 = l >> 1, hf = l & 1;
    #pragma unroll
    for (int o4 = 0; o4 < 4; ++o4) {
        u32x4 vr2 = *(u32x4*)(myLds + ((q2*128 + hf*64 + o4*16) ^ ((q2 & 7) << 4)));
        *(u32x4*)&op[(qw + q2)*Kn + hf*32 + o4*8] = vr2;
    }
}

// ---------------- output projection: 16 rows/block, 4-way K-split + LDS reduce ------
__global__ __launch_bounds__(256) void proj_kernel(
    const unsigned short* __restrict__ attn, const unsigned short* __restrict__ wu_b,
    const float* __restrict__ bu, float* __restrict__ outp)
{
    __shared__ float red[4*16*66];
    const int r0 = blockIdx.x * 16;
    const int tid = threadIdx.x;
    const int w = tid >> 6, l = tid & 63;
    const int lr = l & 15, lh = l >> 4;
    f32x4 acc[4] = {};
    const int r = r0 + lr;
    const int bb = r >> 11, tt = r & 2047;
    #pragma unroll
    for (int ki = 0; ki < 4; ++ki) {
        int kk = w*4 + ki;
        int ch = kk*32 + lh*8;
        int hh = ch >> 6, dd = ch & 63;
        bf16x8 a = *(const bf16x8*)&attn[(size_t)((bb*Hn + hh)*Tn + tt)*Kn + dd];
        #pragma unroll
        for (int n = 0; n < 4; ++n) {
            bf16x8 bf = *(const bf16x8*)&wu_b[(n*16 + lr)*CHn + ch];
            acc[n] = __builtin_amdgcn_mfma_f32_16x16x32_bf16(a, bf, acc[n], 0, 0, 0);
        }
    }
    #pragma unroll
    for (int n = 0; n < 4; ++n)
        #pragma unroll
        for (int reg = 0; reg < 4; ++reg)
            red[w*1056 + (lh*4 + reg)*66 + n*16 + lr] = acc[n][reg];
    __syncthreads();
    #pragma unroll
    for (int it = 0; it < 4; ++it) {
        int idx = tid + it*256;
        int rl = idx >> 6, ko = idx & 63;
        float s = red[rl*66 + ko] + red[1056 + rl*66 + ko]
                + red[2112 + rl*66 + ko] + red[3168 + rl*66 + ko] + bu[ko];
        outp[(size_t)(r0 + rl)*Kn + ko] = s;
    }
}

extern "C" void kernel_launch(void* const* d_in, const int* in_sizes, int n_in,
                              void* d_out, int out_size, void* d_ws, size_t ws_size,
                              hipStream_t stream)
{
    const float* x  = (const float*)d_in[0];
    const float* wq = (const float*)d_in[1];
    const float* bq = (const float*)d_in[2];
    const float* wk = (const float*)d_in[3];
    const float* bk = (const float*)d_in[4];
    const float* wv = (const float*)d_in[5];
    const float* wu = (const float*)d_in[6];
    const float* bu = (const float*)d_in[7];
    float* outp = (float*)d_out;

    char* ws = (char*)d_ws;
    size_t off = 0;
    auto alloc = [&](size_t bytes) {
        char* p = ws + off;
        off = (off + bytes + 255) & ~(size_t)255;
        return p;
    };
    unsigned short* x_pad = (unsigned short*)alloc((size_t)Bn*TPADn*Kn*2);
    unsigned short* w2q  = (unsigned short*)alloc((size_t)KSn*CHn*Kn*2);
    unsigned short* w2k  = (unsigned short*)alloc((size_t)KSn*CHn*Kn*2);
    unsigned short* w2v  = (unsigned short*)alloc((size_t)KSn*CHn*Kn*2);
    unsigned short* wu_b = (unsigned short*)alloc((size_t)CHn*Kn*2);
    float*  bqs = (float*)alloc(CHn*4);
    float*  bks = (float*)alloc(CHn*4);
    unsigned short* q_s  = (unsigned short*)alloc((size_t)Bn*Hn*Tn*Kn*2);
    unsigned short* k_s  = (unsigned short*)alloc((size_t)Bn*Hn*Tn*Kn*2);
    unsigned short* v_t  = (unsigned short*)alloc((size_t)Bn*Hn*Tn*Kn*2);
    unsigned short* attn = (unsigned short*)alloc((size_t)Bn*Tn*CHn*2);

    prep_kernel<<<2048, 256, 0, stream>>>(x, wq, bq, wk, bk, wv, wu,
                                          x_pad, w2q, w2k, w2v, wu_b, bqs, bks);
    conv_v4<<<dim3(4, 8, 24), 256, 0, stream>>>(
        x_pad, w2q, w2k, w2v, bqs, bks, q_s, k_s, v_t);
    attn_kernel<<<1536, 256, 0, stream>>>(q_s, k_s, v_t, attn);
    proj_kernel<<<(Bn*Tn)/16, 256, 0, stream>>>(attn, wu_b, bu, outp);
}

// Round 12
// 127.608 us; speedup vs baseline: 1.4127x; 1.0124x over previous
//
#include <hip/hip_runtime.h>
#include <hip/hip_bf16.h>

typedef __attribute__((ext_vector_type(8))) short bf16x8;
typedef __attribute__((ext_vector_type(4))) float f32x4;
typedef __attribute__((ext_vector_type(16))) float f32x16;
typedef __attribute__((ext_vector_type(4))) unsigned int u32x4;
typedef __attribute__((ext_vector_type(2))) unsigned int u32x2;

#define Bn 8
#define Tn 2048
#define Kn 64
#define Hn 8
#define KSn 5
#define CHn 512
#define TPADn 2052  /* 4 zero rows + 2048 */

__device__ __forceinline__ unsigned short f2bf(float f) {
    unsigned int x = __builtin_bit_cast(unsigned int, f);
    unsigned int r = (x + 0x7fffu + ((x >> 16) & 1u)) >> 16;
    return (unsigned short)r;
}

__device__ __forceinline__ unsigned int cvt_pk_bf16(float lo, float hi) {
    unsigned int r;
    asm("v_cvt_pk_bf16_f32 %0, %1, %2" : "=v"(r) : "v"(lo), "v"(hi));
    return r;
}

__device__ __forceinline__ float fast_exp2(float x) {
#if __has_builtin(__builtin_amdgcn_exp2f)
    return __builtin_amdgcn_exp2f(x);
#else
    float r;
    asm("v_exp_f32 %0, %1" : "=v"(r) : "v"(x));
    return r;
#endif
}

// cross-half (lane ^ 32) merges: validated shfl_xor path (rounds 1-4,7-11).
__device__ __forceinline__ float xhalf_max(float v) {
    return fmaxf(v, __shfl_xor(v, 32));
}
__device__ __forceinline__ float xhalf_add(float v) {
    return v + __shfl_xor(v, 32);
}

// distinct-operand two-register permute (validated in P-repack since round 1)
__device__ __forceinline__ u32x2 pl32swap(unsigned int x, unsigned int y) {
#if __has_builtin(__builtin_amdgcn_permlane32_swap)
    return __builtin_amdgcn_permlane32_swap(x, y, false, false);
#else
    unsigned int xs = (unsigned int)__shfl_xor((int)x, 32);
    unsigned int ys = (unsigned int)__shfl_xor((int)y, 32);
    int hi = (threadIdx.x & 63) >> 5;
    u32x2 r;
    r[0] = hi ? ys : x;   // {x.lo | y.lo}
    r[1] = hi ? y : xs;   // {x.hi | y.hi}
    return r;
#endif
}

__device__ __forceinline__ void gload_lds16(const void* g, void* l) {
    __builtin_amdgcn_global_load_lds(
        (const __attribute__((address_space(1))) void*)g,
        (__attribute__((address_space(3))) void*)l, 16, 0, 0);
}

// ---------------- prep: conversions + padded x + weight reformat + scale folding ----
__global__ void prep_kernel(const float* __restrict__ x,
                            const float* __restrict__ wq, const float* __restrict__ bq,
                            const float* __restrict__ wk, const float* __restrict__ bk,
                            const float* __restrict__ wv,
                            const float* __restrict__ wu,
                            unsigned short* __restrict__ x_pad,
                            unsigned short* __restrict__ w2q, unsigned short* __restrict__ w2k,
                            unsigned short* __restrict__ w2v,
                            unsigned short* __restrict__ wu_b,
                            float* __restrict__ bqs, float* __restrict__ bks)
{
    // 64^-0.25 * sqrt(log2(e)): scores come out pre-multiplied by log2(e)
    const float inv_scale = 0.424660900144f;
    const int N0 = Bn*TPADn*Kn;
    const int N1 = KSn*CHn*Kn;
    const int total = N0 + 3*N1 + CHn*Kn + 2*CHn;
    for (int i = blockIdx.x*blockDim.x + threadIdx.x; i < total; i += gridDim.x*blockDim.x) {
        if (i < N0) {
            int b = i / (TPADn*Kn);
            int rem = i - b*(TPADn*Kn);
            int p = rem >> 6, ic = rem & 63;
            x_pad[i] = (p < 4) ? (unsigned short)0
                               : f2bf(x[((size_t)b*Tn + (p - 4))*Kn + ic]);
            continue;
        }
        int r = i - N0;
        if (r < 3*N1) {
            int conv = r / N1; int rr = r - conv*N1;
            int j = rr / (CHn*Kn); int rc = rr - j*(CHn*Kn);
            int c = rc >> 6; int ic = rc & 63;
            const float* w = (conv==0) ? wq : ((conv==1) ? wk : wv);
            float s = (conv==2) ? 1.0f : inv_scale;
            unsigned short* dst = (conv==0) ? w2q : ((conv==1) ? w2k : w2v);
            dst[rr] = f2bf(w[(c*Kn + ic)*KSn + j] * s);
            continue;
        }
        r -= 3*N1;
        if (r < CHn*Kn) { wu_b[r] = f2bf(wu[r]); continue; }
        r -= CHn*Kn;
        if (r < CHn) { bqs[r] = bq[r]*inv_scale; continue; }
        r -= CHn;
        bks[r] = bk[r]*inv_scale;
    }
}

// ---------------- conv v4: register weights, LDS-staged x (dbuf), 8 t-tiles/block ---
__global__ __launch_bounds__(256) void conv_v4(
    const unsigned short* __restrict__ x_pad,
    const unsigned short* __restrict__ w2q, const unsigned short* __restrict__ w2k,
    const unsigned short* __restrict__ w2v,
    const float* __restrict__ bqs, const float* __restrict__ bks,
    unsigned short* __restrict__ q_s, unsigned short* __restrict__ k_s,
    unsigned short* __restrict__ v_t)
{
    __shared__ __align__(16) unsigned short xs[2][72*64];
    __shared__ __align__(16) unsigned short ts[64*64];
    const int tg = blockIdx.x;
    const int c0 = blockIdx.y * 64;
    const int zz = blockIdx.z;
    const int conv = zz >> 3, b = zz & 7;
    const unsigned short* w2 = (conv==0) ? w2q : ((conv==1) ? w2k : w2v);
    const float* bias = (conv==0) ? bqs : ((conv==1) ? bks : nullptr);
    unsigned short* outp = (conv==0) ? q_s : ((conv==1) ? k_s : v_t);
    const int tid = threadIdx.x;
    const int wid = tid >> 6, l = tid & 63;
    const int lr = l & 15, lh = l >> 4;
    const int wt = wid & 1, wc = wid >> 1;

    bf16x8 wf[5][2][2];
    #pragma unroll
    for (int j = 0; j < 5; ++j)
        #pragma unroll
        for (int kk = 0; kk < 2; ++kk)
            #pragma unroll
            for (int n2 = 0; n2 < 2; ++n2)
                wf[j][kk][n2] = *(const bf16x8*)
                    &w2[(j*CHn + c0 + wc*32 + n2*16 + lr)*Kn + kk*32 + lh*8];
    float bv0 = bias ? bias[c0 + wc*32 + lr]      : 0.0f;
    float bv1 = bias ? bias[c0 + wc*32 + 16 + lr] : 0.0f;

    const int swz_row = l >> 3;
    const int src_inrow = ((l & 7) << 4) ^ (swz_row << 4);

    int buf = 0;
    {
        const char* base = (const char*)(x_pad + (size_t)b*TPADn*Kn);
        int p0 = tg*512;
        for (int i = wid; i < 9; i += 4) {
            const char* src = base + (size_t)(p0 + i*8 + swz_row)*128 + src_inrow;
            gload_lds16(src, (char*)&xs[0][0] + i*1024);
        }
    }
    __syncthreads();

    for (int tt = 0; tt < 8; ++tt) {
        const int t0 = (tg*8 + tt)*64;
        if (tt < 7) {
            const char* base = (const char*)(x_pad + (size_t)b*TPADn*Kn);
            int p0 = t0 + 64;
            for (int i = wid; i < 9; i += 4) {
                const char* src = base + (size_t)(p0 + i*8 + swz_row)*128 + src_inrow;
                gload_lds16(src, (char*)&xs[buf^1][0] + i*1024);
            }
        }
        const char* xb = (const char*)&xs[buf][0];
        f32x4 acc[2][2] = {};
        #pragma unroll
        for (int j = 0; j < 5; ++j)
            #pragma unroll
            for (int kk = 0; kk < 2; ++kk) {
                #pragma unroll
                for (int m = 0; m < 2; ++m) {
                    int row = wt*32 + m*16 + lr + j;
                    bf16x8 a = *(const bf16x8*)
                        (xb + row*128 + ((kk*64 + lh*16) ^ ((row & 7) << 4)));
                    acc[m][0] = __builtin_amdgcn_mfma_f32_16x16x32_bf16(a, wf[j][kk][0], acc[m][0], 0, 0, 0);
                    acc[m][1] = __builtin_amdgcn_mfma_f32_16x16x32_bf16(a, wf[j][kk][1], acc[m][1], 0, 0, 0);
                }
            }
        __syncthreads();
        #pragma unroll
        for (int m = 0; m < 2; ++m)
            #pragma unroll
            for (int n2 = 0; n2 < 2; ++n2) {
                float bv = n2 ? bv1 : bv0;
                int cl = wc*32 + n2*16 + lr;
                #pragma unroll
                for (int reg = 0; reg < 4; ++reg) {
                    int tl = wt*32 + m*16 + lh*4 + reg;
                    ts[(tl*64 + cl) ^ ((tl & 7) << 3)] = f2bf(acc[m][n2][reg] + bv);
                }
            }
        __syncthreads();
        if (conv < 2) {
            #pragma unroll
            for (int it = 0; it < 2; ++it) {
                int idx = tid + it*256;
                int tl = idx >> 3, hl = idx & 7;
                unsigned short tmp[8];
                #pragma unroll
                for (int dl = 0; dl < 8; ++dl)
                    tmp[dl] = ts[(tl*64 + hl + 8*dl) ^ ((tl & 7) << 3)];
                size_t el = ((size_t)(b*Hn + hl)*Tn + t0 + tl)*Kn + (c0 >> 3);
                *(u32x4*)&outp[el] = *(u32x4*)tmp;
            }
        } else {
            #pragma unroll
            for (int it = 0; it < 2; ++it) {
                int idx = tid + it*256;
                int tc = idx >> 6, cl2 = idx & 63;
                int hl = cl2 & 7, dl = cl2 >> 3;
                unsigned short tmp[8];
                #pragma unroll
                for (int i2 = 0; i2 < 8; ++i2)
                    tmp[i2] = ts[((tc*8 + i2)*64 + cl2) ^ (((tc*8 + i2) & 7) << 3)];
                size_t el = ((size_t)(b*Hn + hl)*Kn + (c0 >> 3) + dl)*Tn + t0 + tc*8;
                *(u32x4*)&outp[el] = *(u32x4*)tmp;
            }
        }
        buf ^= 1;
    }
}

// ---- attn v10: conflict-free stV, 32KB LDS (5 blk/CU), deferred l-merge ------------
__global__ __launch_bounds__(256, 3) void attn_kernel(
    const unsigned short* __restrict__ q_s, const unsigned short* __restrict__ k_s,
    const unsigned short* __restrict__ v_t, unsigned short* __restrict__ attn2)
{
    __shared__ __align__(16) unsigned char lds_raw[32768];  // 4 x 8KB wave slots
    const int tid = threadIdx.x;
    const int wid = tid >> 6, l = tid & 63;
    const int lq = l & 31, hi = l >> 5;
    const int bx = blockIdx.x;                   // 1536 blocks, heavy (split) first
    const int bh = (bx & 7)*8 + ((bx >> 3) & 7); // 8 heads per XCD (K+V fits L2)
    const int kb = bx >> 6;                      // 0..23
    int c, t0, t1, role;                         // role: 0 solo, 1 merger, 2 writer
    if (kb < 16) {   // split block: chunks {32+kb, 63-kb}; per pair: halves
        c = (wid < 2) ? (32 + kb) : (63 - kb);
        int L = c + 1, mid = L >> 1, h = wid & 1;
        t0 = h ? mid : 0; t1 = h ? L : mid;
        role = h ? 2 : 1;
    } else {         // solo block: chunks {i, 15-i, 16+i, 31-i}, constant total
        int i = kb - 16;
        c = (wid == 0) ? i : (wid == 1) ? 15 - i : (wid == 2) ? 16 + i : 31 - i;
        t0 = 0; t1 = c + 1; role = 0;
    }
    const int qw = c * 32;
    const unsigned short* qp = q_s + (size_t)bh*Tn*Kn;
    const char* kpc = (const char*)(k_s + (size_t)bh*Tn*Kn);
    const char* vpc = (const char*)(v_t + (size_t)bh*Kn*Tn);
    unsigned short* op = attn2 + (size_t)bh*Tn*Kn;
    const int qg = qw + lq;

    char* stK = (char*)lds_raw + wid*8192;   // [32 keys][64 d], 128B rows, col^row&7
    char* stV = stK + 4096;                  // [32 dp][128B]: (d>>1,d&1,s4^((d>>1)&3))

    // loop-invariant per-lane source offsets (stage chunk i adds i*1024 / i*65536)
    const int kSrcOff = (l >> 3)*128 + (((l & 7) ^ (l >> 3)) << 4);
    const int vSrcOff = (l >> 3)*8192 + ((l >> 2) & 1)*4096
                      + ((((l & 3) ^ ((l >> 3) & 3))) << 4);
    const char* ktp = kpc + (size_t)t0*4096 + kSrcOff;  // next K tile to stage
    const char* vtp = vpc + (size_t)t0*64   + vSrcOff;  // next V tile to stage
    auto stage = [&]() {
        gload_lds16(ktp,           stK);
        gload_lds16(ktp + 1024,    stK + 1024);
        gload_lds16(ktp + 2048,    stK + 2048);
        gload_lds16(ktp + 3072,    stK + 3072);
        gload_lds16(vtp,           stV);
        gload_lds16(vtp + 65536,   stV + 1024);
        gload_lds16(vtp + 131072,  stV + 2048);
        gload_lds16(vtp + 196608,  stV + 3072);
        ktp += 4096; vtp += 64;
    };

    bf16x8 qf[4];
    #pragma unroll
    for (int m = 0; m < 4; ++m)
        qf[m] = *(const bf16x8*)&qp[(qw + lq)*Kn + m*16 + hi*8];

    f32x16 o0 = (f32x16)(0.0f), o1 = (f32x16)(0.0f);
    float m_run = -1e30f, l_run = 0.f;   // l_run is per-lane-HALF (merged at end)

    // V read: per-lane invariant base (conflict-free: 8-lane phases tile 128B)
    const int vReadBase = (lq >> 1)*128 + (lq & 1)*64;
    const int vSwz = (lq >> 1) & 3;

    stage();
    for (int t = t0; t < t1; ++t) {
        asm volatile("s_waitcnt vmcnt(0)" ::: "memory");  // stage(t) landed
        __builtin_amdgcn_sched_barrier(0);
        bf16x8 kbf[4], vbf[2][2];
        #pragma unroll
        for (int m = 0; m < 4; ++m)
            kbf[m] = *(const bf16x8*)(stK + lq*128 + ((m*32 + hi*16) ^ ((lq & 7) << 4)));
        #pragma unroll
        for (int dn = 0; dn < 2; ++dn)
            #pragma unroll
            for (int ks = 0; ks < 2; ++ks)
                vbf[dn][ks] = *(const bf16x8*)
                    (stV + dn*2048 + vReadBase + (((ks*2 + hi) ^ vSwz) << 4));
        asm volatile("s_waitcnt lgkmcnt(0)" ::: "memory"); // reads done before overwrite
        __builtin_amdgcn_sched_barrier(0);
        if (t + 1 < t1) stage();                           // async fill under compute
        __builtin_amdgcn_sched_barrier(0);
        // QK^T (swapped): C[s][q], one q-column per lane
        const int s0 = t*32;
        f32x16 s = (f32x16)(0.0f);
        #pragma unroll
        for (int m = 0; m < 4; ++m)
            s = __builtin_amdgcn_mfma_f32_32x32x16_bf16(kbf[m], qf[m], s, 0, 0, 0);
        if (t == c) {
            #pragma unroll
            for (int r = 0; r < 16; ++r) {
                int sg = s0 + (r & 3) + 8*(r >> 2) + 4*hi;
                if (sg > qg) s[r] = -1e30f;
            }
        }
        float a8[8];
        #pragma unroll
        for (int r = 0; r < 8; ++r) a8[r] = fmaxf(s[r], s[r + 8]);
        float a4_0 = fmaxf(a8[0], a8[4]), a4_1 = fmaxf(a8[1], a8[5]);
        float a4_2 = fmaxf(a8[2], a8[6]), a4_3 = fmaxf(a8[3], a8[7]);
        float mt = fmaxf(fmaxf(a4_0, a4_1), fmaxf(a4_2, a4_3));
        mt = xhalf_max(mt);
        if (!__all(mt <= m_run + 8.0f)) {   // defer-max (log2 domain, THR=8)
            float mn = fmaxf(m_run, mt);
            float alpha = fast_exp2(m_run - mn);
            m_run = mn;
            l_run *= alpha;
            #pragma unroll
            for (int r = 0; r < 16; ++r) { o0[r] *= alpha; o1[r] *= alpha; }
        }
        float ps[4] = {0.f, 0.f, 0.f, 0.f};
        #pragma unroll
        for (int r = 0; r < 16; ++r) {
            float p = fast_exp2(s[r] - m_run);
            s[r] = p;
            ps[r & 3] += p;
        }
        l_run += (ps[0] + ps[1]) + (ps[2] + ps[3]);   // half-local; merged at end
        unsigned int W[8];
        #pragma unroll
        for (int rp = 0; rp < 8; ++rp)
            W[rp] = cvt_pk_bf16(s[2*rp], s[2*rp + 1]);
        u32x4 bw[2];
        #pragma unroll
        for (int m = 0; m < 2; ++m)
            #pragma unroll
            for (int jp = 0; jp < 2; ++jp) {
                u32x2 sw = pl32swap(W[jp + 4*m], W[jp + 4*m + 2]);
                bw[m][jp]     = sw[0];
                bw[m][jp + 2] = sw[1];
            }
        o0 = __builtin_amdgcn_mfma_f32_32x32x16_bf16(vbf[0][0], __builtin_bit_cast(bf16x8, bw[0]), o0, 0, 0, 0);
        o0 = __builtin_amdgcn_mfma_f32_32x32x16_bf16(vbf[0][1], __builtin_bit_cast(bf16x8, bw[1]), o0, 0, 0, 0);
        o1 = __builtin_amdgcn_mfma_f32_32x32x16_bf16(vbf[1][0], __builtin_bit_cast(bf16x8, bw[0]), o1, 0, 0, 0);
        o1 = __builtin_amdgcn_mfma_f32_32x32x16_bf16(vbf[1][1], __builtin_bit_cast(bf16x8, bw[1]), o1, 0, 0, 0);
    }

    // ---- half-split merge (two barriers; m,l parked in merger's dead slot) --------
    if (role == 2) {
        float* po = (float*)stK;                       // own 8KB slot (dead stage)
        #pragma unroll
        for (int r = 0; r < 16; ++r) {
            po[r*64 + l]        = o0[r];
            po[(16 + r)*64 + l] = o1[r];
        }
    }
    if (role) __syncthreads();                         // mergers done reading own slot
    if (role == 2) {
        float* pml = (float*)(lds_raw + (wid - 1)*8192);
        pml[l] = m_run; pml[64 + l] = l_run;
    }
    if (role) __syncthreads();
    if (role == 2) return;
    if (role == 1) {
        const float* po  = (const float*)(lds_raw + (wid + 1)*8192);
        const float* pml = (const float*)(lds_raw + wid*8192);
        float m2 = pml[l], l2 = pml[64 + l];
        float mf = fmaxf(m_run, m2);
        float a1 = fast_exp2(m_run - mf), a2 = fast_exp2(m2 - mf);
        l_run = l_run*a1 + l2*a2;
        #pragma unroll
        for (int r = 0; r < 16; ++r) {
            o0[r] = o0[r]*a1 + po[r*64 + l]*a2;
            o1[r] = o1[r]*a1 + po[(16 + r)*64 + l]*a2;
        }
    }

    // epilogue: merge l across halves once, normalize, LDS transpose, 16B stores
    float l_full = xhalf_add(l_run);
    char* myLds = stK;
    float inv_l = 1.0f / l_full;
    #pragma unroll
    for (int e = 0; e < 16; e += 2) {
        int dd = (e & 3) + 8*(e >> 2) + 4*hi;
        unsigned int wv0 = cvt_pk_bf16(o0[e]*inv_l, o0[e+1]*inv_l);
        *(unsigned int*)(myLds + ((lq*128 + dd*2)      ^ ((lq & 7) << 4))) = wv0;
        unsigned int wv1 = cvt_pk_bf16(o1[e]*inv_l, o1[e+1]*inv_l);
        *(unsigned int*)(myLds + ((lq*128 + 64 + dd*2) ^ ((lq & 7) << 4))) = wv1;
    }
    int q2 = l >> 1, hf = l & 1;
    #pragma unroll
    for (int o4 = 0; o4 < 4; ++o4) {
        u32x4 vr2 = *(u32x4*)(myLds + ((q2*128 + hf*64 + o4*16) ^ ((q2 & 7) << 4)));
        *(u32x4*)&op[(qw + q2)*Kn + hf*32 + o4*8] = vr2;
    }
}

// ---------------- output projection: 16 rows/block, 4-way K-split + LDS reduce ------
__global__ __launch_bounds__(256) void proj_kernel(
    const unsigned short* __restrict__ attn, const unsigned short* __restrict__ wu_b,
    const float* __restrict__ bu, float* __restrict__ outp)
{
    __shared__ float red[4*16*66];
    const int r0 = blockIdx.x * 16;
    const int tid = threadIdx.x;
    const int w = tid >> 6, l = tid & 63;
    const int lr = l & 15, lh = l >> 4;
    f32x4 acc[4] = {};
    const int r = r0 + lr;
    const int bb = r >> 11, tt = r & 2047;
    #pragma unroll
    for (int ki = 0; ki < 4; ++ki) {
        int kk = w*4 + ki;
        int ch = kk*32 + lh*8;
        int hh = ch >> 6, dd = ch & 63;
        bf16x8 a = *(const bf16x8*)&attn[(size_t)((bb*Hn + hh)*Tn + tt)*Kn + dd];
        #pragma unroll
        for (int n = 0; n < 4; ++n) {
            bf16x8 bf = *(const bf16x8*)&wu_b[(n*16 + lr)*CHn + ch];
            acc[n] = __builtin_amdgcn_mfma_f32_16x16x32_bf16(a, bf, acc[n], 0, 0, 0);
        }
    }
    #pragma unroll
    for (int n = 0; n < 4; ++n)
        #pragma unroll
        for (int reg = 0; reg < 4; ++reg)
            red[w*1056 + (lh*4 + reg)*66 + n*16 + lr] = acc[n][reg];
    __syncthreads();
    #pragma unroll
    for (int it = 0; it < 4; ++it) {
        int idx = tid + it*256;
        int rl = idx >> 6, ko = idx & 63;
        float s = red[rl*66 + ko] + red[1056 + rl*66 + ko]
                + red[2112 + rl*66 + ko] + red[3168 + rl*66 + ko] + bu[ko];
        outp[(size_t)(r0 + rl)*Kn + ko] = s;
    }
}

extern "C" void kernel_launch(void* const* d_in, const int* in_sizes, int n_in,
                              void* d_out, int out_size, void* d_ws, size_t ws_size,
                              hipStream_t stream)
{
    const float* x  = (const float*)d_in[0];
    const float* wq = (const float*)d_in[1];
    const float* bq = (const float*)d_in[2];
    const float* wk = (const float*)d_in[3];
    const float* bk = (const float*)d_in[4];
    const float* wv = (const float*)d_in[5];
    const float* wu = (const float*)d_in[6];
    const float* bu = (const float*)d_in[7];
    float* outp = (float*)d_out;

    char* ws = (char*)d_ws;
    size_t off = 0;
    auto alloc = [&](size_t bytes) {
        char* p = ws + off;
        off = (off + bytes + 255) & ~(size_t)255;
        return p;
    };
    unsigned short* x_pad = (unsigned short*)alloc((size_t)Bn*TPADn*Kn*2);
    unsigned short* w2q  = (unsigned short*)alloc((size_t)KSn*CHn*Kn*2);
    unsigned short* w2k  = (unsigned short*)alloc((size_t)KSn*CHn*Kn*2);
    unsigned short* w2v  = (unsigned short*)alloc((size_t)KSn*CHn*Kn*2);
    unsigned short* wu_b = (unsigned short*)alloc((size_t)CHn*Kn*2);
    float*  bqs = (float*)alloc(CHn*4);
    float*  bks = (float*)alloc(CHn*4);
    unsigned short* q_s  = (unsigned short*)alloc((size_t)Bn*Hn*Tn*Kn*2);
    unsigned short* k_s  = (unsigned short*)alloc((size_t)Bn*Hn*Tn*Kn*2);
    unsigned short* v_t  = (unsigned short*)alloc((size_t)Bn*Hn*Tn*Kn*2);
    unsigned short* attn = (unsigned short*)alloc((size_t)Bn*Tn*CHn*2);

    prep_kernel<<<2048, 256, 0, stream>>>(x, wq, bq, wk, bk, wv, wu,
                                          x_pad, w2q, w2k, w2v, wu_b, bqs, bks);
    conv_v4<<<dim3(4, 8, 24), 256, 0, stream>>>(
        x_pad, w2q, w2k, w2v, bqs, bks, q_s, k_s, v_t);
    attn_kernel<<<1536, 256, 0, stream>>>(q_s, k_s, v_t, attn);
    proj_kernel<<<(Bn*Tn)/16, 256, 0, stream>>>(attn, wu_b, bu, outp);
}

// Round 14
// 126.886 us; speedup vs baseline: 1.4207x; 1.0057x over previous
//
#include <hip/hip_runtime.h>
#include <hip/hip_bf16.h>

typedef __attribute__((ext_vector_type(8))) short bf16x8;
typedef __attribute__((ext_vector_type(4))) float f32x4;
typedef __attribute__((ext_vector_type(16))) float f32x16;
typedef __attribute__((ext_vector_type(4))) unsigned int u32x4;
typedef __attribute__((ext_vector_type(2))) unsigned int u32x2;

#define Bn 8
#define Tn 2048
#define Kn 64
#define Hn 8
#define KSn 5
#define CHn 512
#define TPADn 2052  /* 4 zero rows + 2048 */

__device__ __forceinline__ unsigned short f2bf(float f) {
    unsigned int x = __builtin_bit_cast(unsigned int, f);
    unsigned int r = (x + 0x7fffu + ((x >> 16) & 1u)) >> 16;
    return (unsigned short)r;
}

__device__ __forceinline__ unsigned int cvt_pk_bf16(float lo, float hi) {
    unsigned int r;
    asm("v_cvt_pk_bf16_f32 %0, %1, %2" : "=v"(r) : "v"(lo), "v"(hi));
    return r;
}

__device__ __forceinline__ float fast_exp2(float x) {
#if __has_builtin(__builtin_amdgcn_exp2f)
    return __builtin_amdgcn_exp2f(x);
#else
    float r;
    asm("v_exp_f32 %0, %1" : "=v"(r) : "v"(x));
    return r;
#endif
}

// cross-half (lane ^ 32) merges: validated shfl_xor path (rounds 1-4,7-12).
__device__ __forceinline__ float xhalf_max(float v) {
    return fmaxf(v, __shfl_xor(v, 32));
}
__device__ __forceinline__ float xhalf_add(float v) {
    return v + __shfl_xor(v, 32);
}

// distinct-operand two-register permute (validated in P-repack since round 1)
__device__ __forceinline__ u32x2 pl32swap(unsigned int x, unsigned int y) {
#if __has_builtin(__builtin_amdgcn_permlane32_swap)
    return __builtin_amdgcn_permlane32_swap(x, y, false, false);
#else
    unsigned int xs = (unsigned int)__shfl_xor((int)x, 32);
    unsigned int ys = (unsigned int)__shfl_xor((int)y, 32);
    int hi = (threadIdx.x & 63) >> 5;
    u32x2 r;
    r[0] = hi ? ys : x;   // {x.lo | y.lo}
    r[1] = hi ? y : xs;   // {x.hi | y.hi}
    return r;
#endif
}

__device__ __forceinline__ void gload_lds16(const void* g, void* l) {
    __builtin_amdgcn_global_load_lds(
        (const __attribute__((address_space(1))) void*)g,
        (__attribute__((address_space(3))) void*)l, 16, 0, 0);
}

// ---------------- prep: conversions + padded x + weight reformat + scale folding ----
__global__ void prep_kernel(const float* __restrict__ x,
                            const float* __restrict__ wq, const float* __restrict__ bq,
                            const float* __restrict__ wk, const float* __restrict__ bk,
                            const float* __restrict__ wv,
                            const float* __restrict__ wu,
                            unsigned short* __restrict__ x_pad,
                            unsigned short* __restrict__ w2q, unsigned short* __restrict__ w2k,
                            unsigned short* __restrict__ w2v,
                            unsigned short* __restrict__ wu_b,
                            float* __restrict__ bqs, float* __restrict__ bks)
{
    // 64^-0.25 * sqrt(log2(e)): scores come out pre-multiplied by log2(e)
    const float inv_scale = 0.424660900144f;
    const int N0 = Bn*TPADn*Kn;
    const int N1 = KSn*CHn*Kn;
    const int total = N0 + 3*N1 + CHn*Kn + 2*CHn;
    for (int i = blockIdx.x*blockDim.x + threadIdx.x; i < total; i += gridDim.x*blockDim.x) {
        if (i < N0) {
            int b = i / (TPADn*Kn);
            int rem = i - b*(TPADn*Kn);
            int p = rem >> 6, ic = rem & 63;
            x_pad[i] = (p < 4) ? (unsigned short)0
                               : f2bf(x[((size_t)b*Tn + (p - 4))*Kn + ic]);
            continue;
        }
        int r = i - N0;
        if (r < 3*N1) {
            int conv = r / N1; int rr = r - conv*N1;
            int j = rr / (CHn*Kn); int rc = rr - j*(CHn*Kn);
            int c = rc >> 6; int ic = rc & 63;
            const float* w = (conv==0) ? wq : ((conv==1) ? wk : wv);
            float s = (conv==2) ? 1.0f : inv_scale;
            unsigned short* dst = (conv==0) ? w2q : ((conv==1) ? w2k : w2v);
            dst[rr] = f2bf(w[(c*Kn + ic)*KSn + j] * s);
            continue;
        }
        r -= 3*N1;
        if (r < CHn*Kn) { wu_b[r] = f2bf(wu[r]); continue; }
        r -= CHn*Kn;
        if (r < CHn) { bqs[r] = bq[r]*inv_scale; continue; }
        r -= CHn;
        bks[r] = bk[r]*inv_scale;
    }
}

// ---------------- conv v4: register weights, LDS-staged x (dbuf), 8 t-tiles/block ---
__global__ __launch_bounds__(256) void conv_v4(
    const unsigned short* __restrict__ x_pad,
    const unsigned short* __restrict__ w2q, const unsigned short* __restrict__ w2k,
    const unsigned short* __restrict__ w2v,
    const float* __restrict__ bqs, const float* __restrict__ bks,
    unsigned short* __restrict__ q_s, unsigned short* __restrict__ k_s,
    unsigned short* __restrict__ v_t)
{
    __shared__ __align__(16) unsigned short xs[2][72*64];
    __shared__ __align__(16) unsigned short ts[64*64];
    const int tg = blockIdx.x;
    const int c0 = blockIdx.y * 64;
    const int zz = blockIdx.z;
    const int conv = zz >> 3, b = zz & 7;
    const unsigned short* w2 = (conv==0) ? w2q : ((conv==1) ? w2k : w2v);
    const float* bias = (conv==0) ? bqs : ((conv==1) ? bks : nullptr);
    unsigned short* outp = (conv==0) ? q_s : ((conv==1) ? k_s : v_t);
    const int tid = threadIdx.x;
    const int wid = tid >> 6, l = tid & 63;
    const int lr = l & 15, lh = l >> 4;
    const int wt = wid & 1, wc = wid >> 1;

    bf16x8 wf[5][2][2];
    #pragma unroll
    for (int j = 0; j < 5; ++j)
        #pragma unroll
        for (int kk = 0; kk < 2; ++kk)
            #pragma unroll
            for (int n2 = 0; n2 < 2; ++n2)
                wf[j][kk][n2] = *(const bf16x8*)
                    &w2[(j*CHn + c0 + wc*32 + n2*16 + lr)*Kn + kk*32 + lh*8];
    float bv0 = bias ? bias[c0 + wc*32 + lr]      : 0.0f;
    float bv1 = bias ? bias[c0 + wc*32 + 16 + lr] : 0.0f;

    const int swz_row = l >> 3;
    const int src_inrow = ((l & 7) << 4) ^ (swz_row << 4);

    int buf = 0;
    {
        const char* base = (const char*)(x_pad + (size_t)b*TPADn*Kn);
        int p0 = tg*512;
        for (int i = wid; i < 9; i += 4) {
            const char* src = base + (size_t)(p0 + i*8 + swz_row)*128 + src_inrow;
            gload_lds16(src, (char*)&xs[0][0] + i*1024);
        }
    }
    __syncthreads();

    for (int tt = 0; tt < 8; ++tt) {
        const int t0 = (tg*8 + tt)*64;
        if (tt < 7) {
            const char* base = (const char*)(x_pad + (size_t)b*TPADn*Kn);
            int p0 = t0 + 64;
            for (int i = wid; i < 9; i += 4) {
                const char* src = base + (size_t)(p0 + i*8 + swz_row)*128 + src_inrow;
                gload_lds16(src, (char*)&xs[buf^1][0] + i*1024);
            }
        }
        const char* xb = (const char*)&xs[buf][0];
        f32x4 acc[2][2] = {};
        #pragma unroll
        for (int j = 0; j < 5; ++j)
            #pragma unroll
            for (int kk = 0; kk < 2; ++kk) {
                #pragma unroll
                for (int m = 0; m < 2; ++m) {
                    int row = wt*32 + m*16 + lr + j;
                    bf16x8 a = *(const bf16x8*)
                        (xb + row*128 + ((kk*64 + lh*16) ^ ((row & 7) << 4)));
                    acc[m][0] = __builtin_amdgcn_mfma_f32_16x16x32_bf16(a, wf[j][kk][0], acc[m][0], 0, 0, 0);
                    acc[m][1] = __builtin_amdgcn_mfma_f32_16x16x32_bf16(a, wf[j][kk][1], acc[m][1], 0, 0, 0);
                }
            }
        __syncthreads();
        #pragma unroll
        for (int m = 0; m < 2; ++m)
            #pragma unroll
            for (int n2 = 0; n2 < 2; ++n2) {
                float bv = n2 ? bv1 : bv0;
                int cl = wc*32 + n2*16 + lr;
                #pragma unroll
                for (int reg = 0; reg < 4; ++reg) {
                    int tl = wt*32 + m*16 + lh*4 + reg;
                    ts[(tl*64 + cl) ^ ((tl & 7) << 3)] = f2bf(acc[m][n2][reg] + bv);
                }
            }
        __syncthreads();
        if (conv < 2) {
            #pragma unroll
            for (int it = 0; it < 2; ++it) {
                int idx = tid + it*256;
                int tl = idx >> 3, hl = idx & 7;
                unsigned short tmp[8];
                #pragma unroll
                for (int dl = 0; dl < 8; ++dl)
                    tmp[dl] = ts[(tl*64 + hl + 8*dl) ^ ((tl & 7) << 3)];
                size_t el = ((size_t)(b*Hn + hl)*Tn + t0 + tl)*Kn + (c0 >> 3);
                *(u32x4*)&outp[el] = *(u32x4*)tmp;
            }
        } else {
            #pragma unroll
            for (int it = 0; it < 2; ++it) {
                int idx = tid + it*256;
                int tc = idx >> 6, cl2 = idx & 63;
                int hl = cl2 & 7, dl = cl2 >> 3;
                unsigned short tmp[8];
                #pragma unroll
                for (int i2 = 0; i2 < 8; ++i2)
                    tmp[i2] = ts[((tc*8 + i2)*64 + cl2) ^ (((tc*8 + i2) & 7) << 3)];
                size_t el = ((size_t)(b*Hn + hl)*Kn + (c0 >> 3) + dl)*Tn + t0 + tc*8;
                *(u32x4*)&outp[el] = *(u32x4*)tmp;
            }
        }
        buf ^= 1;
    }
}

// ---- attn v10b: round-12-validated body; half-split extended to chunks 16..63 ------
__global__ __launch_bounds__(256, 3) void attn_kernel(
    const unsigned short* __restrict__ q_s, const unsigned short* __restrict__ k_s,
    const unsigned short* __restrict__ v_t, unsigned short* __restrict__ attn2)
{
    __shared__ __align__(16) unsigned char lds_raw[32768];  // 4 x 8KB wave slots
    const int tid = threadIdx.x;
    const int wid = tid >> 6, l = tid & 63;
    const int lq = l & 31, hi = l >> 5;
    const int bx = blockIdx.x;                   // 1792 blocks, longest first
    const int bh = (bx & 7)*8 + ((bx >> 3) & 7); // 8 heads per XCD (K+V fits L2)
    const int kb = bx >> 6;                      // 0..27
    int c, t0, t1, role;                         // role: 0 solo, 1 merger, 2 writer
    if (kb < 24) {   // split block: chunks {16+kb, 63-kb}; wave pairs (0,1),(2,3)
        c = (wid < 2) ? (16 + kb) : (63 - kb);
        int L = c + 1, mid = L >> 1, h = wid & 1;
        t0 = h ? mid : 0; t1 = h ? L : mid;
        role = h ? 2 : 1;
    } else {         // solo block: chunks {i, 7-i, 8+i, 15-i}, max chain 16
        int i = kb - 24;
        c = (wid == 0) ? i : (wid == 1) ? 7 - i : (wid == 2) ? 8 + i : 15 - i;
        t0 = 0; t1 = c + 1; role = 0;
    }
    const int qw = c * 32;
    const unsigned short* qp = q_s + (size_t)bh*Tn*Kn;
    const char* kpc = (const char*)(k_s + (size_t)bh*Tn*Kn);
    const char* vpc = (const char*)(v_t + (size_t)bh*Kn*Tn);
    unsigned short* op = attn2 + (size_t)bh*Tn*Kn;
    const int qg = qw + lq;

    char* stK = (char*)lds_raw + wid*8192;   // [32 keys][64 d], 128B rows, col^row&7
    char* stV = stK + 4096;                  // [32 dp][128B]: (d>>1,d&1,s4^((d>>1)&3))

    // loop-invariant per-lane source offsets (stage chunk i adds i*1024 / i*65536)
    const int kSrcOff = (l >> 3)*128 + (((l & 7) ^ (l >> 3)) << 4);
    const int vSrcOff = (l >> 3)*8192 + ((l >> 2) & 1)*4096
                      + ((((l & 3) ^ ((l >> 3) & 3))) << 4);
    const char* ktp = kpc + (size_t)t0*4096 + kSrcOff;  // next K tile to stage
    const char* vtp = vpc + (size_t)t0*64   + vSrcOff;  // next V tile to stage
    auto stage = [&]() {
        gload_lds16(ktp,           stK);
        gload_lds16(ktp + 1024,    stK + 1024);
        gload_lds16(ktp + 2048,    stK + 2048);
        gload_lds16(ktp + 3072,    stK + 3072);
        gload_lds16(vtp,           stV);
        gload_lds16(vtp + 65536,   stV + 1024);
        gload_lds16(vtp + 131072,  stV + 2048);
        gload_lds16(vtp + 196608,  stV + 3072);
        ktp += 4096; vtp += 64;
    };

    bf16x8 qf[4];
    #pragma unroll
    for (int m = 0; m < 4; ++m)
        qf[m] = *(const bf16x8*)&qp[(qw + lq)*Kn + m*16 + hi*8];

    f32x16 o0 = (f32x16)(0.0f), o1 = (f32x16)(0.0f);
    float m_run = -1e30f, l_run = 0.f;   // l_run is per-lane-HALF (merged at end)

    // V read: per-lane invariant base (conflict-free: 8-lane phases tile 128B)
    const int vReadBase = (lq >> 1)*128 + (lq & 1)*64;
    const int vSwz = (lq >> 1) & 3;

    stage();
    for (int t = t0; t < t1; ++t) {
        asm volatile("s_waitcnt vmcnt(0)" ::: "memory");  // stage(t) landed
        __builtin_amdgcn_sched_barrier(0);
        bf16x8 kbf[4], vbf[2][2];
        #pragma unroll
        for (int m = 0; m < 4; ++m)
            kbf[m] = *(const bf16x8*)(stK + lq*128 + ((m*32 + hi*16) ^ ((lq & 7) << 4)));
        #pragma unroll
        for (int dn = 0; dn < 2; ++dn)
            #pragma unroll
            for (int ks = 0; ks < 2; ++ks)
                vbf[dn][ks] = *(const bf16x8*)
                    (stV + dn*2048 + vReadBase + (((ks*2 + hi) ^ vSwz) << 4));
        asm volatile("s_waitcnt lgkmcnt(0)" ::: "memory"); // reads done before overwrite
        __builtin_amdgcn_sched_barrier(0);
        if (t + 1 < t1) stage();                           // async fill under compute
        __builtin_amdgcn_sched_barrier(0);
        // QK^T (swapped): C[s][q], one q-column per lane
        const int s0 = t*32;
        f32x16 s = (f32x16)(0.0f);
        #pragma unroll
        for (int m = 0; m < 4; ++m)
            s = __builtin_amdgcn_mfma_f32_32x32x16_bf16(kbf[m], qf[m], s, 0, 0, 0);
        if (t == c) {
            #pragma unroll
            for (int r = 0; r < 16; ++r) {
                int sg = s0 + (r & 3) + 8*(r >> 2) + 4*hi;
                if (sg > qg) s[r] = -1e30f;
            }
        }
        float a8[8];
        #pragma unroll
        for (int r = 0; r < 8; ++r) a8[r] = fmaxf(s[r], s[r + 8]);
        float a4_0 = fmaxf(a8[0], a8[4]), a4_1 = fmaxf(a8[1], a8[5]);
        float a4_2 = fmaxf(a8[2], a8[6]), a4_3 = fmaxf(a8[3], a8[7]);
        float mt = fmaxf(fmaxf(a4_0, a4_1), fmaxf(a4_2, a4_3));
        mt = xhalf_max(mt);
        if (!__all(mt <= m_run + 8.0f)) {   // defer-max (log2 domain, THR=8)
            float mn = fmaxf(m_run, mt);
            float alpha = fast_exp2(m_run - mn);
            m_run = mn;
            l_run *= alpha;
            #pragma unroll
            for (int r = 0; r < 16; ++r) { o0[r] *= alpha; o1[r] *= alpha; }
        }
        float ps[4] = {0.f, 0.f, 0.f, 0.f};
        #pragma unroll
        for (int r = 0; r < 16; ++r) {
            float p = fast_exp2(s[r] - m_run);
            s[r] = p;
            ps[r & 3] += p;
        }
        l_run += (ps[0] + ps[1]) + (ps[2] + ps[3]);   // half-local; merged at end
        unsigned int W[8];
        #pragma unroll
        for (int rp = 0; rp < 8; ++rp)
            W[rp] = cvt_pk_bf16(s[2*rp], s[2*rp + 1]);
        u32x4 bw[2];
        #pragma unroll
        for (int m = 0; m < 2; ++m)
            #pragma unroll
            for (int jp = 0; jp < 2; ++jp) {
                u32x2 sw = pl32swap(W[jp + 4*m], W[jp + 4*m + 2]);
                bw[m][jp]     = sw[0];
                bw[m][jp + 2] = sw[1];
            }
        o0 = __builtin_amdgcn_mfma_f32_32x32x16_bf16(vbf[0][0], __builtin_bit_cast(bf16x8, bw[0]), o0, 0, 0, 0);
        o0 = __builtin_amdgcn_mfma_f32_32x32x16_bf16(vbf[0][1], __builtin_bit_cast(bf16x8, bw[1]), o0, 0, 0, 0);
        o1 = __builtin_amdgcn_mfma_f32_32x32x16_bf16(vbf[1][0], __builtin_bit_cast(bf16x8, bw[0]), o1, 0, 0, 0);
        o1 = __builtin_amdgcn_mfma_f32_32x32x16_bf16(vbf[1][1], __builtin_bit_cast(bf16x8, bw[1]), o1, 0, 0, 0);
    }

    // ---- half-split merge (two barriers; m,l parked in merger's dead slot) --------
    if (role == 2) {
        float* po = (float*)stK;                       // own 8KB slot (dead stage)
        #pragma unroll
        for (int r = 0; r < 16; ++r) {
            po[r*64 + l]        = o0[r];
            po[(16 + r)*64 + l] = o1[r];
        }
    }
    if (role) __syncthreads();                         // mergers done reading own slot
    if (role == 2) {
        float* pml = (float*)(lds_raw + (wid - 1)*8192);
        pml[l] = m_run; pml[64 + l] = l_run;
    }
    if (role) __syncthreads();
    if (role == 2) return;
    if (role == 1) {
        const float* po  = (const float*)(lds_raw + (wid + 1)*8192);
        const float* pml = (const float*)(lds_raw + wid*8192);
        float m2 = pml[l], l2 = pml[64 + l];
        float mf = fmaxf(m_run, m2);
        float a1 = fast_exp2(m_run - mf), a2 = fast_exp2(m2 - mf);
        l_run = l_run*a1 + l2*a2;
        #pragma unroll
        for (int r = 0; r < 16; ++r) {
            o0[r] = o0[r]*a1 + po[r*64 + l]*a2;
            o1[r] = o1[r]*a1 + po[(16 + r)*64 + l]*a2;
        }
    }

    // epilogue: merge l across halves once, normalize, LDS transpose, 16B stores
    float l_full = xhalf_add(l_run);
    char* myLds = stK;
    float inv_l = 1.0f / l_full;
    #pragma unroll
    for (int e = 0; e < 16; e += 2) {
        int dd = (e & 3) + 8*(e >> 2) + 4*hi;
        unsigned int wv0 = cvt_pk_bf16(o0[e]*inv_l, o0[e+1]*inv_l);
        *(unsigned int*)(myLds + ((lq*128 + dd*2)      ^ ((lq & 7) << 4))) = wv0;
        unsigned int wv1 = cvt_pk_bf16(o1[e]*inv_l, o1[e+1]*inv_l);
        *(unsigned int*)(myLds + ((lq*128 + 64 + dd*2) ^ ((lq & 7) << 4))) = wv1;
    }
    int q2 = l >> 1, hf = l & 1;
    #pragma unroll
    for (int o4 = 0; o4 < 4; ++o4) {
        u32x4 vr2 = *(u32x4*)(myLds + ((q2*128 + hf*64 + o4*16) ^ ((q2 & 7) << 4)));
        *(u32x4*)&op[(qw + q2)*Kn + hf*32 + o4*8] = vr2;
    }
}

// ---------------- output projection: 16 rows/block, 4-way K-split + LDS reduce ------
__global__ __launch_bounds__(256) void proj_kernel(
    const unsigned short* __restrict__ attn, const unsigned short* __restrict__ wu_b,
    const float* __restrict__ bu, float* __restrict__ outp)
{
    __shared__ float red[4*16*66];
    const int r0 = blockIdx.x * 16;
    const int tid = threadIdx.x;
    const int w = tid >> 6, l = tid & 63;
    const int lr = l & 15, lh = l >> 4;
    f32x4 acc[4] = {};
    const int r = r0 + lr;
    const int bb = r >> 11, tt = r & 2047;
    #pragma unroll
    for (int ki = 0; ki < 4; ++ki) {
        int kk = w*4 + ki;
        int ch = kk*32 + lh*8;
        int hh = ch >> 6, dd = ch & 63;
        bf16x8 a = *(const bf16x8*)&attn[(size_t)((bb*Hn + hh)*Tn + tt)*Kn + dd];
        #pragma unroll
        for (int n = 0; n < 4; ++n) {
            bf16x8 bf = *(const bf16x8*)&wu_b[(n*16 + lr)*CHn + ch];
            acc[n] = __builtin_amdgcn_mfma_f32_16x16x32_bf16(a, bf, acc[n], 0, 0, 0);
        }
    }
    #pragma unroll
    for (int n = 0; n < 4; ++n)
        #pragma unroll
        for (int reg = 0; reg < 4; ++reg)
            red[w*1056 + (lh*4 + reg)*66 + n*16 + lr] = acc[n][reg];
    __syncthreads();
    #pragma unroll
    for (int it = 0; it < 4; ++it) {
        int idx = tid + it*256;
        int rl = idx >> 6, ko = idx & 63;
        float s = red[rl*66 + ko] + red[1056 + rl*66 + ko]
                + red[2112 + rl*66 + ko] + red[3168 + rl*66 + ko] + bu[ko];
        outp[(size_t)(r0 + rl)*Kn + ko] = s;
    }
}

extern "C" void kernel_launch(void* const* d_in, const int* in_sizes, int n_in,
                              void* d_out, int out_size, void* d_ws, size_t ws_size,
                              hipStream_t stream)
{
    const float* x  = (const float*)d_in[0];
    const float* wq = (const float*)d_in[1];
    const float* bq = (const float*)d_in[2];
    const float* wk = (const float*)d_in[3];
    const float* bk = (const float*)d_in[4];
    const float* wv = (const float*)d_in[5];
    const float* wu = (const float*)d_in[6];
    const float* bu = (const float*)d_in[7];
    float* outp = (float*)d_out;

    char* ws = (char*)d_ws;
    size_t off = 0;
    auto alloc = [&](size_t bytes) {
        char* p = ws + off;
        off = (off + bytes + 255) & ~(size_t)255;
        return p;
    };
    unsigned short* x_pad = (unsigned short*)alloc((size_t)Bn*TPADn*Kn*2);
    unsigned short* w2q  = (unsigned short*)alloc((size_t)KSn*CHn*Kn*2);
    unsigned short* w2k  = (unsigned short*)alloc((size_t)KSn*CHn*Kn*2);
    unsigned short* w2v  = (unsigned short*)alloc((size_t)KSn*CHn*Kn*2);
    unsigned short* wu_b = (unsigned short*)alloc((size_t)CHn*Kn*2);
    float*  bqs = (float*)alloc(CHn*4);
    float*  bks = (float*)alloc(CHn*4);
    unsigned short* q_s  = (unsigned short*)alloc((size_t)Bn*Hn*Tn*Kn*2);
    unsigned short* k_s  = (unsigned short*)alloc((size_t)Bn*Hn*Tn*Kn*2);
    unsigned short* v_t  = (unsigned short*)alloc((size_t)Bn*Hn*Tn*Kn*2);
    unsigned short* attn = (unsigned short*)alloc((size_t)Bn*Tn*CHn*2);

    prep_kernel<<<2048, 256, 0, stream>>>(x, wq, bq, wk, bk, wv, wu,
                                          x_pad, w2q, w2k, w2v, wu_b, bqs, bks);
    conv_v4<<<dim3(4, 8, 24), 256, 0, stream>>>(
        x_pad, w2q, w2k, w2v, bqs, bks, q_s, k_s, v_t);
    attn_kernel<<<1792, 256, 0, stream>>>(q_s, k_s, v_t, attn);
    proj_kernel<<<(Bn*Tn)/16, 256, 0, stream>>>(attn, wu_b, bu, outp);
}